// Round 1
// baseline (15002.356 us; speedup 1.0000x reference)
//
#include <hip/hip_runtime.h>
#include <math.h>

#define Bn   128
#define Ln   512
#define Hn   336
#define Dn   256
#define TXTn 768
#define Kn   16
#define Sn   4
#define EMBn 128
#define SHIFT 56      // max(1, H//6)
#define HTile 16      // Hn/HTile = 21

// ---------- helpers ----------
__device__ __forceinline__ void atomicAddD(double* addr, double val){
  unsigned long long* a = (unsigned long long*)addr;
  unsigned long long old = *a, assumed;
  do {
    assumed = old;
    old = atomicCAS(a, assumed,
                    __double_as_longlong(val + __longlong_as_double(assumed)));
  } while (assumed != old);
}

__device__ __forceinline__ float softplusf(float x){
  return fmaxf(x, 0.f) + log1pf(expf(-fabsf(x)));
}

// ---------- 1. text -> kernel params (mu/sig/amp/shape_w) + ent + tv ----------
__global__ void k_t2k(const float* __restrict__ text, const float* __restrict__ W,
                      const float* __restrict__ bb,
                      float* __restrict__ mu_o, float* __restrict__ sig_o,
                      float* __restrict__ amp_o, float* __restrict__ shw_o,
                      double* __restrict__ acc){
  int b = blockIdx.x, t = threadIdx.x;
  __shared__ float te[TXTn];
  __shared__ float raw[Kn*7];
  __shared__ float mus[Kn];
  for (int i = t; i < TXTn; i += 128) te[i] = text[(size_t)b*TXTn + i];
  __syncthreads();
  if (t < Kn*7){
    float s = bb[t];
    for (int i = 0; i < TXTn; ++i) s += te[i]*W[i*(Kn*7) + t];
    raw[t] = s;
  }
  __syncthreads();
  if (t < Kn){
    float r0 = raw[t*7+0], r1 = raw[t*7+1], r2 = raw[t*7+2];
    float mu  = 1.f/(1.f+expf(-r0));
    float sig = softplusf(r1)*0.15f + 1e-3f;
    float amp = softplusf(r2);
    float s0 = raw[t*7+3], s1 = raw[t*7+4], s2 = raw[t*7+5], s3 = raw[t*7+6];
    float m = fmaxf(fmaxf(s0,s1), fmaxf(s2,s3));
    float e0 = expf(s0-m), e1 = expf(s1-m), e2 = expf(s2-m), e3 = expf(s3-m);
    float inv = 1.f/(e0+e1+e2+e3);
    float w0 = e0*inv, w1 = e1*inv, w2 = e2*inv, w3 = e3*inv;
    int bk = b*Kn + t;
    mu_o[bk] = mu; sig_o[bk] = sig; amp_o[bk] = amp;
    shw_o[bk*4+0] = w0; shw_o[bk*4+1] = w1; shw_o[bk*4+2] = w2; shw_o[bk*4+3] = w3;
    mus[t] = mu;
    float ent = 0.f, sw;
    sw = fmaxf(w0,1e-8f); ent += sw*logf(sw);
    sw = fmaxf(w1,1e-8f); ent += sw*logf(sw);
    sw = fmaxf(w2,1e-8f); ent += sw*logf(sw);
    sw = fmaxf(w3,1e-8f); ent += sw*logf(sw);
    atomicAddD(acc+3, (double)ent);
  }
  __syncthreads();
  if (t == 0){
    float tv = 0.f;
    for (int k = 1; k < Kn; ++k) tv += fabsf(mus[k]-mus[k-1]);
    atomicAddD(acc+4, (double)tv);
  }
}

// ---------- 2. kappa[b,k,h] + raw row-mass ----------
__global__ void k_kappa(const float* __restrict__ mu_i, const float* __restrict__ sig_i,
                        const float* __restrict__ amp_i, const float* __restrict__ shw,
                        float* __restrict__ kap_o, float* __restrict__ rr_o){
  int bk = blockIdx.x, t = threadIdx.x;
  float mu = mu_i[bk], sig = sig_i[bk], amp = amp_i[bk];
  float w0 = shw[bk*4+0], w1 = shw[bk*4+1], w2 = shw[bk*4+2], w3 = shw[bk*4+3];
  float part = 0.f;
  for (int h = t; h < Hn; h += 128){
    float tt = (h + 0.5f)/(float)Hn;
    float z  = (tt - mu)/sig;
    float az = fabsf(z);
    float b0 = expf(-0.5f*z*z);
    float b1 = expf(-az);
    float b2 = fmaxf(1.f-az, 0.f);
    float zc = fminf(fmaxf(z,-1.f),1.f);
    float b3 = (az <= 1.f) ? 0.5f*(1.f+cosf(3.14159265358979f*zc)) : 0.f;
    float kv = amp*(w0*b0 + w1*b1 + w2*b2 + w3*b3);
    kap_o[(size_t)bk*Hn + h] = kv;
    part += kv;
  }
  __shared__ float red[128];
  red[t] = part; __syncthreads();
  for (int s = 64; s > 0; s >>= 1){ if (t < s) red[t] += red[t+s]; __syncthreads(); }
  if (t == 0) rr_o[bk] = red[0] + 1e-6f;
}

// ---------- 3. normalize r per batch ----------
__global__ void k_rnorm(float* __restrict__ rr){
  int b = blockIdx.x, t = threadIdx.x;
  __shared__ float v[Kn];
  __shared__ float sum;
  if (t < Kn) v[t] = rr[b*Kn + t];
  __syncthreads();
  if (t == 0){ float s = 0; for (int k = 0; k < Kn; ++k) s += v[k]; sum = s; }
  __syncthreads();
  if (t < Kn) rr[b*Kn + t] = v[t]/sum;
}

// ---------- 4. y_tir_scalar[b,h] = sum_k kappa ----------
__global__ void k_ytir(const float* __restrict__ kap, float* __restrict__ ytirs){
  int idx = blockIdx.x*256 + threadIdx.x;
  if (idx >= Bn*Hn) return;
  int b = idx / Hn, h = idx - b*Hn;
  float s = 0.f;
  for (int k = 0; k < Kn; ++k) s += kap[((size_t)(b*Kn+k))*Hn + h];
  ytirs[idx] = s;
}

// ---------- 5. k_emb = kappa @ W_kemb + b, then l2-normalize ----------
__global__ void k_kemb(const float* __restrict__ kap, const float* __restrict__ W,
                       const float* __restrict__ bb, float* __restrict__ kn_o){
  int bk = blockIdx.x, e = threadIdx.x;  // 128 threads = EMB
  __shared__ float kl[Hn];
  for (int h = e; h < Hn; h += 128) kl[h] = kap[(size_t)bk*Hn + h];
  __syncthreads();
  float s = bb[e];
  for (int h = 0; h < Hn; ++h) s += kl[h]*W[h*EMBn + e];
  __shared__ float red[128];
  red[e] = s*s; __syncthreads();
  for (int st = 64; st > 0; st >>= 1){ if (e < st) red[e] += red[e+st]; __syncthreads(); }
  float inv = 1.f/(sqrtf(red[0]) + 1e-8f);
  kn_o[(size_t)bk*EMBn + e] = s*inv;
}

// ---------- 6. ts_global = mean_l enc_out ----------
__global__ void k_tsg(const float* __restrict__ enc, float* __restrict__ tsg){
  int b = blockIdx.x, t = threadIdx.x;  // 256 threads
  int d4 = t & 63, part = t >> 6;
  const float4* e4 = (const float4*)(enc + (size_t)b*Ln*Dn);
  float4 s = make_float4(0.f,0.f,0.f,0.f);
  for (int l = part; l < Ln; l += 4){
    float4 v = e4[(size_t)l*64 + d4];
    s.x += v.x; s.y += v.y; s.z += v.z; s.w += v.w;
  }
  __shared__ float4 red[256];
  red[t] = s; __syncthreads();
  if (part == 0){
    float4 a = red[d4], b2 = red[64+d4], c = red[128+d4], d = red[192+d4];
    const float inv = 1.f/(float)Ln;
    float4 o;
    o.x = (a.x+b2.x+c.x+d.x)*inv; o.y = (a.y+b2.y+c.y+d.y)*inv;
    o.z = (a.z+b2.z+c.z+d.z)*inv; o.w = (a.w+b2.w+c.w+d.w)*inv;
    ((float4*)tsg)[(size_t)b*64 + d4] = o;
  }
}

// ---------- 7. gate MLP ----------
__global__ void k_gate(const float* __restrict__ tsg, const float* __restrict__ text,
                       const float* __restrict__ vp,
                       const float* __restrict__ W1, const float* __restrict__ b1,
                       const float* __restrict__ W2, const float* __restrict__ b2,
                       float* __restrict__ gate_o){
  int b = blockIdx.x, t = threadIdx.x;  // 512 threads
  __shared__ float gi[2*Dn + TXTn];     // 1280
  __shared__ float hid[512];
  if (t < Dn){ gi[t] = tsg[b*Dn + t]; gi[Dn+TXTn + t] = vp[t]; }
  for (int i = t; i < TXTn; i += 512) gi[Dn + i] = text[(size_t)b*TXTn + i];
  __syncthreads();
  float s = b1[t];
  for (int i = 0; i < 2*Dn+TXTn; ++i) s += gi[i]*W1[i*512 + t];
  hid[t] = fmaxf(s, 0.f);
  __syncthreads();
  if (t < Dn){
    float o = b2[t];
    for (int i = 0; i < 512; ++i) o += hid[i]*W2[i*Dn + t];
    gate_o[b*Dn + t] = 1.f/(1.f+expf(-o));
  }
}

// ---------- 8. f_pos = concat(y,d1,d2) @ W_fp + b_fp  (HTile rows/block) ----------
__global__ void k_fpos(const float* __restrict__ yf, const float* __restrict__ W,
                       const float* __restrict__ bb, float* __restrict__ fpos){
  int b  = blockIdx.x / (Hn/HTile);
  int h0 = (blockIdx.x % (Hn/HTile))*HTile;
  int t  = threadIdx.x;  // 128
  __shared__ float x[HTile*3*Dn];  // [r][768]
  const float* yb = yf + (size_t)b*Hn*Dn;
  for (int idx = t; idx < HTile*Dn; idx += 128){
    int r = idx >> 8, d = idx & 255;
    int h = h0 + r;
    float yh = yb[(size_t)h*Dn + d];
    float y1 = (h >= 1) ? yb[(size_t)(h-1)*Dn + d] : 0.f;
    float y0 = (h >= 2) ? yb[(size_t)(h-2)*Dn + d] : 0.f;
    float d1, d2;
    if (h == 0){ d1 = 0.f; d2 = 0.f; }
    else if (h == 1){ d1 = yh - y1; d2 = d1; }
    else { d1 = yh - y1; d2 = yh - 2.f*y1 + y0; }
    x[r*768 + d] = yh; x[r*768 + 256 + d] = d1; x[r*768 + 512 + d] = d2;
  }
  __syncthreads();
  int e = t;  // 128 = EMB
  float f[HTile];
  #pragma unroll
  for (int r = 0; r < HTile; ++r) f[r] = bb[e];
  for (int i = 0; i < 768; i += 4){
    float w0 = W[(i+0)*EMBn + e];
    float w1 = W[(i+1)*EMBn + e];
    float w2 = W[(i+2)*EMBn + e];
    float w3 = W[(i+3)*EMBn + e];
    #pragma unroll
    for (int r = 0; r < HTile; ++r){
      float4 xv = *(const float4*)&x[r*768 + i];
      f[r] += xv.x*w0 + xv.y*w1 + xv.z*w2 + xv.w*w3;
    }
  }
  #pragma unroll
  for (int r = 0; r < HTile; ++r)
    fpos[((size_t)(b*Hn + h0 + r))*EMBn + e] = f[r];
}

// ---------- 9. 1/(||f_pos row||+1e-8) ----------
__global__ void k_finv(const float* __restrict__ fpos, float* __restrict__ finv){
  int row  = blockIdx.x*2 + (threadIdx.x >> 6);
  int lane = threadIdx.x & 63;
  const float* f = fpos + (size_t)row*EMBn;
  float s = 0.f;
  for (int e = lane; e < EMBn; e += 64){ float v = f[e]; s += v*v; }
  for (int o = 32; o; o >>= 1) s += __shfl_down(s, o);
  if (lane == 0) finv[row] = 1.f/(sqrtf(s) + 1e-8f);
}

// ---------- 10. MSE of gated fusion ----------
__global__ void k_mse(const float* __restrict__ yres, const float* __restrict__ yfut,
                      const float* __restrict__ gate, const float* __restrict__ ytirs,
                      const float* __restrict__ Wt, const float* __restrict__ bt,
                      const float* __restrict__ vp, double* __restrict__ acc){
  const long long total = (long long)Bn*Hn*Dn;
  long long tid = blockIdx.x*(long long)blockDim.x + threadIdx.x;
  long long nth = gridDim.x*(long long)blockDim.x;
  float part = 0.f;
  for (long long i4 = tid; i4*4 < total; i4 += nth){
    long long base = i4*4;
    int b = (int)(base/((long long)Hn*Dn));
    int rem = (int)(base - (long long)b*Hn*Dn);
    int h = rem/Dn, d = rem - h*Dn;
    float4 yr = *(const float4*)(yres + base);
    float4 yv = *(const float4*)(yfut + base);
    float4 g  = *(const float4*)(gate + (size_t)b*Dn + d);
    float4 wt = *(const float4*)(Wt + d);
    float4 bv = *(const float4*)(bt + d);
    float4 vv = *(const float4*)(vp + d);
    float ys = ytirs[b*Hn + h];
    float yt, yh, e;
    yt = (ys*wt.x + bv.x)*vv.x; yh = yr.x + 0.5f*g.x*(yt-yr.x); e = yh-yv.x; part += e*e;
    yt = (ys*wt.y + bv.y)*vv.y; yh = yr.y + 0.5f*g.y*(yt-yr.y); e = yh-yv.y; part += e*e;
    yt = (ys*wt.z + bv.z)*vv.z; yh = yr.z + 0.5f*g.z*(yt-yr.z); e = yh-yv.z; part += e*e;
    yt = (ys*wt.w + bv.w)*vv.w; yh = yr.w + 0.5f*g.w*(yt-yr.w); e = yh-yv.w; part += e*e;
  }
  __shared__ float red[256];
  red[threadIdx.x] = part; __syncthreads();
  for (int s = 128; s > 0; s >>= 1){
    if (threadIdx.x < s) red[threadIdx.x] += red[threadIdx.x + s];
    __syncthreads();
  }
  if (threadIdx.x == 0) atomicAddD(acc+0, (double)red[0]);
}

// ---------- 11. per-batch: C, Sinkhorn, cot, delta-contrastive ----------
__global__ void __launch_bounds__(256)
k_sink(const float* __restrict__ kn, const float* __restrict__ fpos,
       const float* __restrict__ finv, const float* __restrict__ mu_i,
       const float* __restrict__ rr, const int* __restrict__ perm,
       double* __restrict__ acc){
  int b = blockIdx.x, t = threadIdx.x;  // 256 threads
  __shared__ float Cm[Kn*Hn];           // C, later aliased: aggp = Cm[0:2048], agg1 = Cm[2048:4096]
  __shared__ float Km[Kn*Hn];           // Kmat, later w
  __shared__ float vS[Hn];
  __shared__ float uS[Kn], rrS[Kn], musS[Kn], rowS[Kn];
  __shared__ float red[256];
  __shared__ int permS[EMBn];
  float* aggp = Cm;
  float* agg1 = Cm + Kn*EMBn;

  if (t < EMBn) permS[t] = perm[t];
  if (t < Kn){ musS[t] = mu_i[b*Kn + t]; rrS[t] = rr[b*Kn + t]; }
  for (int h = t; h < Hn; h += 256) vS[h] = 1.f;
  __syncthreads();

  // C[k,h] and Kmat = exp(-C/eps)
  for (int p = t; p < Kn*Hn; p += 256){
    int k = p/Hn, h = p - k*Hn;
    const float4* f4 = (const float4*)(fpos + ((size_t)b*Hn + h)*EMBn);
    const float4* k4 = (const float4*)(kn   + ((size_t)b*Kn + k)*EMBn);
    float s = 0.f;
    #pragma unroll 8
    for (int i = 0; i < EMBn/4; ++i){
      float4 a = k4[i], f = f4[i];
      s += a.x*f.x + a.y*f.y + a.z*f.z + a.w*f.w;
    }
    float cs = s*finv[b*Hn + h];
    float th = (h + 0.5f)/(float)Hn;
    float c  = (1.f - cs) + 0.5f*fmaxf(musS[k] - th, 0.f);
    Cm[p] = c;
    Km[p] = expf(-20.f*c);   // 1/EPS = 20
  }
  __syncthreads();

  int wave = t >> 6, lane = t & 63;
  for (int it = 0; it < 30; ++it){
    for (int i = 0; i < 4; ++i){       // u update: 4 rows per wave
      int k = wave*4 + i;
      float s = 0.f;
      for (int h = lane; h < Hn; h += 64) s += Km[k*Hn + h]*vS[h];
      for (int o = 32; o; o >>= 1) s += __shfl_down(s, o);
      if (lane == 0) uS[k] = rrS[k]/(s + 1e-9f);
    }
    __syncthreads();
    for (int h = t; h < Hn; h += 256){ // v update
      float s = 0.f;
      #pragma unroll
      for (int k = 0; k < Kn; ++k) s += Km[k*Hn + h]*uS[k];
      vS[h] = (1.f/(float)Hn)/(s + 1e-9f);
    }
    __syncthreads();
  }

  // row sums of Pi
  for (int i = 0; i < 4; ++i){
    int k = wave*4 + i;
    float s = 0.f;
    for (int h = lane; h < Hn; h += 64) s += Km[k*Hn + h]*vS[h];
    for (int o = 32; o; o >>= 1) s += __shfl_down(s, o);
    if (lane == 0) rowS[k] = uS[k]*s;
  }
  __syncthreads();

  // cot partial + overwrite Km with w = Pi/rowsum
  float cotp = 0.f;
  for (int p = t; p < Kn*Hn; p += 256){
    int k = p/Hn, h = p - k*Hn;
    float Pi = uS[k]*Km[p]*vS[h];
    cotp += Cm[p]*Pi;
    Km[p] = Pi/(rowS[k] + 1e-9f);
  }
  red[t] = cotp; __syncthreads();
  for (int s = 128; s > 0; s >>= 1){ if (t < s) red[t] += red[t+s]; __syncthreads(); }
  if (t == 0) atomicAddD(acc+1, (double)red[0]);
  // all threads synced; Cm free to be reused as agg buffers

  // agg_pos / agg_neg1 (roll(56) expressed as shifted w-index)
  {
    int e = t & 127, kg = t >> 7;
    float ap[8], a1[8];
    #pragma unroll
    for (int j = 0; j < 8; ++j){ ap[j] = 0.f; a1[j] = 0.f; }
    for (int h = 0; h < Hn; ++h){
      float f = fpos[((size_t)b*Hn + h)*EMBn + e];
      int h1 = h + SHIFT; if (h1 >= Hn) h1 -= Hn;
      #pragma unroll
      for (int j = 0; j < 8; ++j){
        int k = kg*8 + j;
        ap[j] += Km[k*Hn + h ]*f;
        a1[j] += Km[k*Hn + h1]*f;
      }
    }
    #pragma unroll
    for (int j = 0; j < 8; ++j){
      int k = kg*8 + j;
      aggp[k*EMBn + e] = ap[j];
      agg1[k*EMBn + e] = a1[j];
    }
  }
  __syncthreads();

  // sims + log-softmax contributions
  float dsum = 0.f;
  for (int i = 0; i < 4; ++i){
    int k = wave*4 + i;
    float sp = 0.f, s1 = 0.f, s2 = 0.f, np = 0.f, n1 = 0.f;
    for (int e = lane; e < EMBn; e += 64){
      float kne = kn[((size_t)b*Kn + k)*EMBn + e];
      float a  = aggp[k*EMBn + e];
      float c1 = agg1[k*EMBn + e];
      sp += kne*a; s1 += kne*c1;
      s2 += kne*aggp[k*EMBn + permS[e]];
      np += a*a; n1 += c1*c1;
    }
    for (int o = 32; o; o >>= 1){
      sp += __shfl_down(sp, o); s1 += __shfl_down(s1, o); s2 += __shfl_down(s2, o);
      np += __shfl_down(np, o); n1 += __shfl_down(n1, o);
    }
    if (lane == 0){
      float ip  = 1.f/(sqrtf(np) + 1e-8f);
      float i1v = 1.f/(sqrtf(n1) + 1e-8f);
      const float ti = 1.f/0.07f;
      float l0 = sp*ip*ti, l1 = s1*i1v*ti, l2 = s2*ip*ti;
      float m = fmaxf(l0, fmaxf(l1, l2));
      float lse = m + logf(expf(l0-m) + expf(l1-m) + expf(l2-m));
      dsum += (lse - l0);
    }
  }
  if (lane == 0) atomicAddD(acc+2, (double)dsum);
}

// ---------- 12. combine ----------
__global__ void k_final(const double* __restrict__ acc, float* __restrict__ out){
  if (threadIdx.x == 0 && blockIdx.x == 0){
    double mse = acc[0]/((double)Bn*Hn*Dn);
    double cot = acc[1]/(double)Bn;
    double del = acc[2]/((double)Bn*Kn);
    double ent = -(acc[3]/((double)Bn*Kn));
    double tv  = acc[4]/((double)Bn*(Kn-1));
    out[0] = (float)(1.0*mse + 0.1*cot + 0.1*del + 0.01*ent + 0.01*tv);
  }
}

// ---------- launch ----------
extern "C" void kernel_launch(void* const* d_in, const int* in_sizes, int n_in,
                              void* d_out, int out_size, void* d_ws, size_t ws_size,
                              hipStream_t stream) {
  const float* y_res  = (const float*)d_in[0];
  const float* text   = (const float*)d_in[1];
  const float* enc    = (const float*)d_in[2];
  const float* yfut   = (const float*)d_in[3];
  const int*   perm   = (const int*)  d_in[4];
  const float* W_t2k  = (const float*)d_in[5];
  const float* b_t2k  = (const float*)d_in[6];
  const float* W_kemb = (const float*)d_in[7];
  const float* b_kemb = (const float*)d_in[8];
  const float* W_tir  = (const float*)d_in[9];
  const float* b_tir  = (const float*)d_in[10];
  const float* vproj  = (const float*)d_in[11];
  const float* W_g1   = (const float*)d_in[12];
  const float* b_g1   = (const float*)d_in[13];
  const float* W_g2   = (const float*)d_in[14];
  const float* b_g2   = (const float*)d_in[15];
  const float* W_fp   = (const float*)d_in[16];
  const float* b_fp   = (const float*)d_in[17];

  double* acc = (double*)d_ws;
  float*  F   = (float*)((char*)d_ws + 64);
  float* mu_w  = F;            // 2048
  float* sig_w = F + 2048;     // 2048
  float* amp_w = F + 4096;     // 2048
  float* shw_w = F + 6144;     // 8192
  float* kap_w = F + 14336;    // 688128
  float* ytr_w = F + 702464;   // 43008
  float* rr_w  = F + 745472;   // 2048
  float* kn_w  = F + 747520;   // 262144
  float* tsg_w = F + 1009664;  // 32768
  float* gate_w= F + 1042432;  // 32768
  float* fp_w  = F + 1075200;  // 5505024
  float* fi_w  = F + 6580224;  // 43008

  hipMemsetAsync(d_ws, 0, 64, stream);  // zero loss accumulators

  k_t2k  <<<Bn, 128, 0, stream>>>(text, W_t2k, b_t2k, mu_w, sig_w, amp_w, shw_w, acc);
  k_kappa<<<Bn*Kn, 128, 0, stream>>>(mu_w, sig_w, amp_w, shw_w, kap_w, rr_w);
  k_rnorm<<<Bn, 64, 0, stream>>>(rr_w);
  k_ytir <<<(Bn*Hn + 255)/256, 256, 0, stream>>>(kap_w, ytr_w);
  k_kemb <<<Bn*Kn, 128, 0, stream>>>(kap_w, W_kemb, b_kemb, kn_w);
  k_tsg  <<<Bn, 256, 0, stream>>>(enc, tsg_w);
  k_gate <<<Bn, 512, 0, stream>>>(tsg_w, text, vproj, W_g1, b_g1, W_g2, b_g2, gate_w);
  k_fpos <<<Bn*(Hn/HTile), 128, 0, stream>>>(yfut, W_fp, b_fp, fp_w);
  k_finv <<<Bn*Hn/2, 128, 0, stream>>>(fp_w, fi_w);
  k_mse  <<<1024, 256, 0, stream>>>(y_res, yfut, gate_w, ytr_w, W_tir, b_tir, vproj, acc);
  k_sink <<<Bn, 256, 0, stream>>>(kn_w, fp_w, fi_w, mu_w, rr_w, perm, acc);
  k_final<<<1, 64, 0, stream>>>(acc, (float*)d_out);
}

// Round 2
// 992.965 us; speedup vs baseline: 15.1086x; 15.1086x over previous
//
#include <hip/hip_runtime.h>
#include <math.h>

#define Bn   128
#define Ln   512
#define Hn   336
#define Dn   256
#define TXTn 768
#define Kn   16
#define Sn   4
#define EMBn 128
#define SHIFT 56      // max(1, H//6)
#define HTile 16      // Hn/HTile = 21
#define MSEB 1024     // k_mse grid

__device__ __forceinline__ float softplusf(float x){
  return fmaxf(x, 0.f) + log1pf(expf(-fabsf(x)));
}

// ---------- 1. text -> kernel params (mu/sig/amp/shape_w) + ent + tv partials ----------
__global__ void k_t2k(const float* __restrict__ text, const float* __restrict__ W,
                      const float* __restrict__ bb,
                      float* __restrict__ mu_o, float* __restrict__ sig_o,
                      float* __restrict__ amp_o, float* __restrict__ shw_o,
                      float* __restrict__ part_ent, float* __restrict__ part_tv){
  int b = blockIdx.x, t = threadIdx.x;
  __shared__ float te[TXTn];
  __shared__ float raw[Kn*7];
  __shared__ float mus[Kn];
  __shared__ float entS[Kn];
  for (int i = t; i < TXTn; i += 128) te[i] = text[(size_t)b*TXTn + i];
  __syncthreads();
  if (t < Kn*7){
    float s = bb[t];
    for (int i = 0; i < TXTn; ++i) s += te[i]*W[i*(Kn*7) + t];
    raw[t] = s;
  }
  __syncthreads();
  if (t < Kn){
    float r0 = raw[t*7+0], r1 = raw[t*7+1], r2 = raw[t*7+2];
    float mu  = 1.f/(1.f+expf(-r0));
    float sig = softplusf(r1)*0.15f + 1e-3f;
    float amp = softplusf(r2);
    float s0 = raw[t*7+3], s1 = raw[t*7+4], s2 = raw[t*7+5], s3 = raw[t*7+6];
    float m = fmaxf(fmaxf(s0,s1), fmaxf(s2,s3));
    float e0 = expf(s0-m), e1 = expf(s1-m), e2 = expf(s2-m), e3 = expf(s3-m);
    float inv = 1.f/(e0+e1+e2+e3);
    float w0 = e0*inv, w1 = e1*inv, w2 = e2*inv, w3 = e3*inv;
    int bk = b*Kn + t;
    mu_o[bk] = mu; sig_o[bk] = sig; amp_o[bk] = amp;
    shw_o[bk*4+0] = w0; shw_o[bk*4+1] = w1; shw_o[bk*4+2] = w2; shw_o[bk*4+3] = w3;
    mus[t] = mu;
    float ent = 0.f, sw;
    sw = fmaxf(w0,1e-8f); ent += sw*logf(sw);
    sw = fmaxf(w1,1e-8f); ent += sw*logf(sw);
    sw = fmaxf(w2,1e-8f); ent += sw*logf(sw);
    sw = fmaxf(w3,1e-8f); ent += sw*logf(sw);
    entS[t] = ent;
  }
  __syncthreads();
  if (t == 0){
    float tv = 0.f, es = 0.f;
    for (int k = 1; k < Kn; ++k) tv += fabsf(mus[k]-mus[k-1]);
    for (int k = 0; k < Kn; ++k) es += entS[k];
    part_tv[b]  = tv;
    part_ent[b] = es;
  }
}

// ---------- 2. kappa[b,k,h] + raw row-mass ----------
__global__ void k_kappa(const float* __restrict__ mu_i, const float* __restrict__ sig_i,
                        const float* __restrict__ amp_i, const float* __restrict__ shw,
                        float* __restrict__ kap_o, float* __restrict__ rr_o){
  int bk = blockIdx.x, t = threadIdx.x;
  float mu = mu_i[bk], sig = sig_i[bk], amp = amp_i[bk];
  float w0 = shw[bk*4+0], w1 = shw[bk*4+1], w2 = shw[bk*4+2], w3 = shw[bk*4+3];
  float part = 0.f;
  for (int h = t; h < Hn; h += 128){
    float tt = (h + 0.5f)/(float)Hn;
    float z  = (tt - mu)/sig;
    float az = fabsf(z);
    float b0 = expf(-0.5f*z*z);
    float b1 = expf(-az);
    float b2 = fmaxf(1.f-az, 0.f);
    float zc = fminf(fmaxf(z,-1.f),1.f);
    float b3 = (az <= 1.f) ? 0.5f*(1.f+cosf(3.14159265358979f*zc)) : 0.f;
    float kv = amp*(w0*b0 + w1*b1 + w2*b2 + w3*b3);
    kap_o[(size_t)bk*Hn + h] = kv;
    part += kv;
  }
  __shared__ float red[128];
  red[t] = part; __syncthreads();
  for (int s = 64; s > 0; s >>= 1){ if (t < s) red[t] += red[t+s]; __syncthreads(); }
  if (t == 0) rr_o[bk] = red[0] + 1e-6f;
}

// ---------- 3. normalize r per batch ----------
__global__ void k_rnorm(float* __restrict__ rr){
  int b = blockIdx.x, t = threadIdx.x;
  __shared__ float v[Kn];
  __shared__ float sum;
  if (t < Kn) v[t] = rr[b*Kn + t];
  __syncthreads();
  if (t == 0){ float s = 0; for (int k = 0; k < Kn; ++k) s += v[k]; sum = s; }
  __syncthreads();
  if (t < Kn) rr[b*Kn + t] = v[t]/sum;
}

// ---------- 4. y_tir_scalar[b,h] = sum_k kappa ----------
__global__ void k_ytir(const float* __restrict__ kap, float* __restrict__ ytirs){
  int idx = blockIdx.x*256 + threadIdx.x;
  if (idx >= Bn*Hn) return;
  int b = idx / Hn, h = idx - b*Hn;
  float s = 0.f;
  for (int k = 0; k < Kn; ++k) s += kap[((size_t)(b*Kn+k))*Hn + h];
  ytirs[idx] = s;
}

// ---------- 5. k_emb = kappa @ W_kemb + b, then l2-normalize ----------
__global__ void k_kemb(const float* __restrict__ kap, const float* __restrict__ W,
                       const float* __restrict__ bb, float* __restrict__ kn_o){
  int bk = blockIdx.x, e = threadIdx.x;  // 128 threads = EMB
  __shared__ float kl[Hn];
  for (int h = e; h < Hn; h += 128) kl[h] = kap[(size_t)bk*Hn + h];
  __syncthreads();
  float s = bb[e];
  for (int h = 0; h < Hn; ++h) s += kl[h]*W[h*EMBn + e];
  __shared__ float red[128];
  red[e] = s*s; __syncthreads();
  for (int st = 64; st > 0; st >>= 1){ if (e < st) red[e] += red[e+st]; __syncthreads(); }
  float inv = 1.f/(sqrtf(red[0]) + 1e-8f);
  kn_o[(size_t)bk*EMBn + e] = s*inv;
}

// ---------- 6. ts_global = mean_l enc_out ----------
__global__ void k_tsg(const float* __restrict__ enc, float* __restrict__ tsg){
  int b = blockIdx.x, t = threadIdx.x;  // 256 threads
  int d4 = t & 63, part = t >> 6;
  const float4* e4 = (const float4*)(enc + (size_t)b*Ln*Dn);
  float4 s = make_float4(0.f,0.f,0.f,0.f);
  for (int l = part; l < Ln; l += 4){
    float4 v = e4[(size_t)l*64 + d4];
    s.x += v.x; s.y += v.y; s.z += v.z; s.w += v.w;
  }
  __shared__ float4 red[256];
  red[t] = s; __syncthreads();
  if (part == 0){
    float4 a = red[d4], b2 = red[64+d4], c = red[128+d4], d = red[192+d4];
    const float inv = 1.f/(float)Ln;
    float4 o;
    o.x = (a.x+b2.x+c.x+d.x)*inv; o.y = (a.y+b2.y+c.y+d.y)*inv;
    o.z = (a.z+b2.z+c.z+d.z)*inv; o.w = (a.w+b2.w+c.w+d.w)*inv;
    ((float4*)tsg)[(size_t)b*64 + d4] = o;
  }
}

// ---------- 7. gate MLP ----------
__global__ void k_gate(const float* __restrict__ tsg, const float* __restrict__ text,
                       const float* __restrict__ vp,
                       const float* __restrict__ W1, const float* __restrict__ b1,
                       const float* __restrict__ W2, const float* __restrict__ b2,
                       float* __restrict__ gate_o){
  int b = blockIdx.x, t = threadIdx.x;  // 512 threads
  __shared__ float gi[2*Dn + TXTn];     // 1280
  __shared__ float hid[512];
  if (t < Dn){ gi[t] = tsg[b*Dn + t]; gi[Dn+TXTn + t] = vp[t]; }
  for (int i = t; i < TXTn; i += 512) gi[Dn + i] = text[(size_t)b*TXTn + i];
  __syncthreads();
  float s = b1[t];
  for (int i = 0; i < 2*Dn+TXTn; ++i) s += gi[i]*W1[i*512 + t];
  hid[t] = fmaxf(s, 0.f);
  __syncthreads();
  if (t < Dn){
    float o = b2[t];
    for (int i = 0; i < 512; ++i) o += hid[i]*W2[i*Dn + t];
    gate_o[b*Dn + t] = 1.f/(1.f+expf(-o));
  }
}

// ---------- 8. f_pos = concat(y,d1,d2) @ W_fp + b_fp  (HTile rows/block) ----------
__global__ void k_fpos(const float* __restrict__ yf, const float* __restrict__ W,
                       const float* __restrict__ bb, float* __restrict__ fpos){
  int b  = blockIdx.x / (Hn/HTile);
  int h0 = (blockIdx.x % (Hn/HTile))*HTile;
  int t  = threadIdx.x;  // 128
  __shared__ float x[HTile*3*Dn];  // [r][768]
  const float* yb = yf + (size_t)b*Hn*Dn;
  for (int idx = t; idx < HTile*Dn; idx += 128){
    int r = idx >> 8, d = idx & 255;
    int h = h0 + r;
    float yh = yb[(size_t)h*Dn + d];
    float y1 = (h >= 1) ? yb[(size_t)(h-1)*Dn + d] : 0.f;
    float y0 = (h >= 2) ? yb[(size_t)(h-2)*Dn + d] : 0.f;
    float d1, d2;
    if (h == 0){ d1 = 0.f; d2 = 0.f; }
    else if (h == 1){ d1 = yh - y1; d2 = d1; }
    else { d1 = yh - y1; d2 = yh - 2.f*y1 + y0; }
    x[r*768 + d] = yh; x[r*768 + 256 + d] = d1; x[r*768 + 512 + d] = d2;
  }
  __syncthreads();
  int e = t;  // 128 = EMB
  float f[HTile];
  #pragma unroll
  for (int r = 0; r < HTile; ++r) f[r] = bb[e];
  for (int i = 0; i < 768; i += 4){
    float w0 = W[(i+0)*EMBn + e];
    float w1 = W[(i+1)*EMBn + e];
    float w2 = W[(i+2)*EMBn + e];
    float w3 = W[(i+3)*EMBn + e];
    #pragma unroll
    for (int r = 0; r < HTile; ++r){
      float4 xv = *(const float4*)&x[r*768 + i];
      f[r] += xv.x*w0 + xv.y*w1 + xv.z*w2 + xv.w*w3;
    }
  }
  #pragma unroll
  for (int r = 0; r < HTile; ++r)
    fpos[((size_t)(b*Hn + h0 + r))*EMBn + e] = f[r];
}

// ---------- 9. 1/(||f_pos row||+1e-8) ----------
__global__ void k_finv(const float* __restrict__ fpos, float* __restrict__ finv){
  int row  = blockIdx.x*2 + (threadIdx.x >> 6);
  int lane = threadIdx.x & 63;
  const float* f = fpos + (size_t)row*EMBn;
  float s = 0.f;
  for (int e = lane; e < EMBn; e += 64){ float v = f[e]; s += v*v; }
  for (int o = 32; o; o >>= 1) s += __shfl_down(s, o);
  if (lane == 0) finv[row] = 1.f/(sqrtf(s) + 1e-8f);
}

// ---------- 10. MSE of gated fusion (per-block partial) ----------
__global__ void k_mse(const float* __restrict__ yres, const float* __restrict__ yfut,
                      const float* __restrict__ gate, const float* __restrict__ ytirs,
                      const float* __restrict__ Wt, const float* __restrict__ bt,
                      const float* __restrict__ vp, float* __restrict__ part_mse){
  const long long total = (long long)Bn*Hn*Dn;
  long long tid = blockIdx.x*(long long)blockDim.x + threadIdx.x;
  long long nth = gridDim.x*(long long)blockDim.x;
  float part = 0.f;
  for (long long i4 = tid; i4*4 < total; i4 += nth){
    long long base = i4*4;
    int b = (int)(base/((long long)Hn*Dn));
    int rem = (int)(base - (long long)b*Hn*Dn);
    int h = rem/Dn, d = rem - h*Dn;
    float4 yr = *(const float4*)(yres + base);
    float4 yv = *(const float4*)(yfut + base);
    float4 g  = *(const float4*)(gate + (size_t)b*Dn + d);
    float4 wt = *(const float4*)(Wt + d);
    float4 bv = *(const float4*)(bt + d);
    float4 vv = *(const float4*)(vp + d);
    float ys = ytirs[b*Hn + h];
    float yt, yh, e;
    yt = (ys*wt.x + bv.x)*vv.x; yh = yr.x + 0.5f*g.x*(yt-yr.x); e = yh-yv.x; part += e*e;
    yt = (ys*wt.y + bv.y)*vv.y; yh = yr.y + 0.5f*g.y*(yt-yr.y); e = yh-yv.y; part += e*e;
    yt = (ys*wt.z + bv.z)*vv.z; yh = yr.z + 0.5f*g.z*(yt-yr.z); e = yh-yv.z; part += e*e;
    yt = (ys*wt.w + bv.w)*vv.w; yh = yr.w + 0.5f*g.w*(yt-yr.w); e = yh-yv.w; part += e*e;
  }
  __shared__ float red[256];
  red[threadIdx.x] = part; __syncthreads();
  for (int s = 128; s > 0; s >>= 1){
    if (threadIdx.x < s) red[threadIdx.x] += red[threadIdx.x + s];
    __syncthreads();
  }
  if (threadIdx.x == 0) part_mse[blockIdx.x] = red[0];
}

// ---------- 11. per-batch: C, Sinkhorn, cot, delta-contrastive (per-block partials) ----------
__global__ void __launch_bounds__(256)
k_sink(const float* __restrict__ kn, const float* __restrict__ fpos,
       const float* __restrict__ finv, const float* __restrict__ mu_i,
       const float* __restrict__ rr, const int* __restrict__ perm,
       float* __restrict__ part_cot, float* __restrict__ part_del){
  int b = blockIdx.x, t = threadIdx.x;  // 256 threads
  __shared__ float Cm[Kn*Hn];           // C, later aliased: aggp/agg1
  __shared__ float Km[Kn*Hn];           // Kmat, later w
  __shared__ float vS[Hn];
  __shared__ float uS[Kn], rrS[Kn], musS[Kn], rowS[Kn];
  __shared__ float red[256];
  __shared__ int permS[EMBn];
  float* aggp = Cm;
  float* agg1 = Cm + Kn*EMBn;

  if (t < EMBn) permS[t] = perm[t];
  if (t < Kn){ musS[t] = mu_i[b*Kn + t]; rrS[t] = rr[b*Kn + t]; }
  for (int h = t; h < Hn; h += 256) vS[h] = 1.f;
  __syncthreads();

  // C[k,h] and Kmat = exp(-C/eps)
  for (int p = t; p < Kn*Hn; p += 256){
    int k = p/Hn, h = p - k*Hn;
    const float4* f4 = (const float4*)(fpos + ((size_t)b*Hn + h)*EMBn);
    const float4* k4 = (const float4*)(kn   + ((size_t)b*Kn + k)*EMBn);
    float s = 0.f;
    #pragma unroll 8
    for (int i = 0; i < EMBn/4; ++i){
      float4 a = k4[i], f = f4[i];
      s += a.x*f.x + a.y*f.y + a.z*f.z + a.w*f.w;
    }
    float cs = s*finv[b*Hn + h];
    float th = (h + 0.5f)/(float)Hn;
    float c  = (1.f - cs) + 0.5f*fmaxf(musS[k] - th, 0.f);
    Cm[p] = c;
    Km[p] = expf(-20.f*c);   // 1/EPS = 20
  }
  __syncthreads();

  int wave = t >> 6, lane = t & 63;
  for (int it = 0; it < 30; ++it){
    for (int i = 0; i < 4; ++i){       // u update: 4 rows per wave
      int k = wave*4 + i;
      float s = 0.f;
      for (int h = lane; h < Hn; h += 64) s += Km[k*Hn + h]*vS[h];
      for (int o = 32; o; o >>= 1) s += __shfl_down(s, o);
      if (lane == 0) uS[k] = rrS[k]/(s + 1e-9f);
    }
    __syncthreads();
    for (int h = t; h < Hn; h += 256){ // v update
      float s = 0.f;
      #pragma unroll
      for (int k = 0; k < Kn; ++k) s += Km[k*Hn + h]*uS[k];
      vS[h] = (1.f/(float)Hn)/(s + 1e-9f);
    }
    __syncthreads();
  }

  // row sums of Pi
  for (int i = 0; i < 4; ++i){
    int k = wave*4 + i;
    float s = 0.f;
    for (int h = lane; h < Hn; h += 64) s += Km[k*Hn + h]*vS[h];
    for (int o = 32; o; o >>= 1) s += __shfl_down(s, o);
    if (lane == 0) rowS[k] = uS[k]*s;
  }
  __syncthreads();

  // cot partial + overwrite Km with w = Pi/rowsum
  float cotp = 0.f;
  for (int p = t; p < Kn*Hn; p += 256){
    int k = p/Hn, h = p - k*Hn;
    float Pi = uS[k]*Km[p]*vS[h];
    cotp += Cm[p]*Pi;
    Km[p] = Pi/(rowS[k] + 1e-9f);
  }
  red[t] = cotp; __syncthreads();
  for (int s = 128; s > 0; s >>= 1){ if (t < s) red[t] += red[t+s]; __syncthreads(); }
  if (t == 0) part_cot[b] = red[0];
  __syncthreads();
  // all threads synced; Cm free to be reused as agg buffers

  // agg_pos / agg_neg1 (roll(56) expressed as shifted w-index)
  {
    int e = t & 127, kg = t >> 7;
    float ap[8], a1[8];
    #pragma unroll
    for (int j = 0; j < 8; ++j){ ap[j] = 0.f; a1[j] = 0.f; }
    for (int h = 0; h < Hn; ++h){
      float f = fpos[((size_t)b*Hn + h)*EMBn + e];
      int h1 = h + SHIFT; if (h1 >= Hn) h1 -= Hn;
      #pragma unroll
      for (int j = 0; j < 8; ++j){
        int k = kg*8 + j;
        ap[j] += Km[k*Hn + h ]*f;
        a1[j] += Km[k*Hn + h1]*f;
      }
    }
    #pragma unroll
    for (int j = 0; j < 8; ++j){
      int k = kg*8 + j;
      aggp[k*EMBn + e] = ap[j];
      agg1[k*EMBn + e] = a1[j];
    }
  }
  __syncthreads();

  // sims + log-softmax contributions
  float dsum = 0.f;
  for (int i = 0; i < 4; ++i){
    int k = wave*4 + i;
    float sp = 0.f, s1 = 0.f, s2 = 0.f, np = 0.f, n1 = 0.f;
    for (int e = lane; e < EMBn; e += 64){
      float kne = kn[((size_t)b*Kn + k)*EMBn + e];
      float a  = aggp[k*EMBn + e];
      float c1 = agg1[k*EMBn + e];
      sp += kne*a; s1 += kne*c1;
      s2 += kne*aggp[k*EMBn + permS[e]];
      np += a*a; n1 += c1*c1;
    }
    for (int o = 32; o; o >>= 1){
      sp += __shfl_down(sp, o); s1 += __shfl_down(s1, o); s2 += __shfl_down(s2, o);
      np += __shfl_down(np, o); n1 += __shfl_down(n1, o);
    }
    if (lane == 0){
      float ip  = 1.f/(sqrtf(np) + 1e-8f);
      float i1v = 1.f/(sqrtf(n1) + 1e-8f);
      const float ti = 1.f/0.07f;
      float l0 = sp*ip*ti, l1 = s1*i1v*ti, l2 = s2*ip*ti;
      float m = fmaxf(l0, fmaxf(l1, l2));
      float lse = m + logf(expf(l0-m) + expf(l1-m) + expf(l2-m));
      dsum += (lse - l0);
    }
  }
  __syncthreads();          // red[] free again
  if (lane == 0) red[wave] = dsum;
  __syncthreads();
  if (t == 0) part_del[b] = red[0] + red[1] + red[2] + red[3];
}

// ---------- 12. combine (single block, parallel reduce of partials) ----------
__global__ void k_final(const float* __restrict__ part_mse, const float* __restrict__ part_cot,
                        const float* __restrict__ part_del, const float* __restrict__ part_ent,
                        const float* __restrict__ part_tv, float* __restrict__ out){
  int t = threadIdx.x;  // 256
  __shared__ double sred[256];
  double m = 0.0;
  for (int i = t; i < MSEB; i += 256) m += (double)part_mse[i];
  double o4 = 0.0;  // cot, del, ent, tv packed: weight them here, sum once
  if (t < Bn){
    o4 = 0.1*(double)part_cot[t] + (0.1/(double)Kn)*(double)part_del[t]
       - (0.01/(double)Kn)*(double)part_ent[t] + (0.01/(double)(Kn-1))*(double)part_tv[t];
  }
  sred[t] = m/((double)Bn*Hn*Dn)*1.0 + o4/(double)Bn;
  __syncthreads();
  for (int s = 128; s > 0; s >>= 1){ if (t < s) sred[t] += sred[t+s]; __syncthreads(); }
  if (t == 0) out[0] = (float)sred[0];
}

// ---------- launch ----------
extern "C" void kernel_launch(void* const* d_in, const int* in_sizes, int n_in,
                              void* d_out, int out_size, void* d_ws, size_t ws_size,
                              hipStream_t stream) {
  const float* y_res  = (const float*)d_in[0];
  const float* text   = (const float*)d_in[1];
  const float* enc    = (const float*)d_in[2];
  const float* yfut   = (const float*)d_in[3];
  const int*   perm   = (const int*)  d_in[4];
  const float* W_t2k  = (const float*)d_in[5];
  const float* b_t2k  = (const float*)d_in[6];
  const float* W_kemb = (const float*)d_in[7];
  const float* b_kemb = (const float*)d_in[8];
  const float* W_tir  = (const float*)d_in[9];
  const float* b_tir  = (const float*)d_in[10];
  const float* vproj  = (const float*)d_in[11];
  const float* W_g1   = (const float*)d_in[12];
  const float* b_g1   = (const float*)d_in[13];
  const float* W_g2   = (const float*)d_in[14];
  const float* b_g2   = (const float*)d_in[15];
  const float* W_fp   = (const float*)d_in[16];
  const float* b_fp   = (const float*)d_in[17];

  float* F = (float*)d_ws;
  float* mu_w   = F;            // 2048
  float* sig_w  = F + 2048;     // 2048
  float* amp_w  = F + 4096;     // 2048
  float* shw_w  = F + 6144;     // 8192
  float* kap_w  = F + 14336;    // 688128
  float* ytr_w  = F + 702464;   // 43008
  float* rr_w   = F + 745472;   // 2048
  float* kn_w   = F + 747520;   // 262144
  float* tsg_w  = F + 1009664;  // 32768
  float* gate_w = F + 1042432;  // 32768
  float* fp_w   = F + 1075200;  // 5505024
  float* fi_w   = F + 6580224;  // 43008
  float* pmse_w = F + 6623232;  // 1024
  float* pcot_w = F + 6624256;  // 128
  float* pdel_w = F + 6624384;  // 128
  float* pent_w = F + 6624512;  // 128
  float* ptv_w  = F + 6624640;  // 128

  k_t2k  <<<Bn, 128, 0, stream>>>(text, W_t2k, b_t2k, mu_w, sig_w, amp_w, shw_w, pent_w, ptv_w);
  k_kappa<<<Bn*Kn, 128, 0, stream>>>(mu_w, sig_w, amp_w, shw_w, kap_w, rr_w);
  k_rnorm<<<Bn, 64, 0, stream>>>(rr_w);
  k_ytir <<<(Bn*Hn + 255)/256, 256, 0, stream>>>(kap_w, ytr_w);
  k_kemb <<<Bn*Kn, 128, 0, stream>>>(kap_w, W_kemb, b_kemb, kn_w);
  k_tsg  <<<Bn, 256, 0, stream>>>(enc, tsg_w);
  k_gate <<<Bn, 512, 0, stream>>>(tsg_w, text, vproj, W_g1, b_g1, W_g2, b_g2, gate_w);
  k_fpos <<<Bn*(Hn/HTile), 128, 0, stream>>>(yfut, W_fp, b_fp, fp_w);
  k_finv <<<Bn*Hn/2, 128, 0, stream>>>(fp_w, fi_w);
  k_mse  <<<MSEB, 256, 0, stream>>>(y_res, yfut, gate_w, ytr_w, W_tir, b_tir, vproj, pmse_w);
  k_sink <<<Bn, 256, 0, stream>>>(kn_w, fp_w, fi_w, mu_w, rr_w, perm, pcot_w, pdel_w);
  k_final<<<1, 256, 0, stream>>>(pmse_w, pcot_w, pdel_w, pent_w, ptv_w, (float*)d_out);
}

// Round 4
// 782.454 us; speedup vs baseline: 19.1735x; 1.2690x over previous
//
#include <hip/hip_runtime.h>
#include <math.h>

#define Bn   128
#define Ln   512
#define Hn   336
#define Dn   256
#define TXTn 768
#define Kn   16
#define EMBn 128
#define SHIFT 56      // max(1, H//6)
#define FT   48       // fpos rows per block
#define RT   24       // fpos rows per wave-pair (half block)
#define NT   7        // Hn / FT
#define MSEB 1024

__device__ __forceinline__ float dot4(float4 a, float4 b){
  return a.x*b.x + a.y*b.y + a.z*b.z + a.w*b.w;
}

__device__ __forceinline__ float softplusf(float x){
  return fmaxf(x, 0.f) + log1pf(expf(-fabsf(x)));
}

// ---------- 1. fused: text->params, kappa, rr(normalized), ytir, ent/tv partials ----------
__global__ __launch_bounds__(128) void k_fused1(
    const float* __restrict__ text, const float* __restrict__ W, const float* __restrict__ bb,
    float* __restrict__ mu_o, float* __restrict__ kapT, float* __restrict__ rr_o,
    float* __restrict__ ytirs, float* __restrict__ part_ent, float* __restrict__ part_tv){
  int b = blockIdx.x, t = threadIdx.x;
  __shared__ float kapS[Kn*Hn];
  __shared__ float musL[Kn], sigL[Kn], ampL[Kn], shwL[Kn*4], entS[Kn], rrS[Kn];
  __shared__ float red[128];
  __shared__ float totS;
  // raw = text@W + b  (112 outputs; text read via wave-uniform scalar loads)
  if (t < Kn*7){
    float s = bb[t];
    const float* tb = text + (size_t)b*TXTn;
    for (int i = 0; i < TXTn; i += 4){
      float4 x = *(const float4*)(tb + i);
      s += x.x*W[(i+0)*112 + t] + x.y*W[(i+1)*112 + t]
         + x.z*W[(i+2)*112 + t] + x.w*W[(i+3)*112 + t];
    }
    red[t] = s;
  }
  __syncthreads();
  if (t < Kn){
    float r0 = red[t*7+0], r1 = red[t*7+1], r2 = red[t*7+2];
    float mu  = 1.f/(1.f+expf(-r0));
    float sig = softplusf(r1)*0.15f + 1e-3f;
    float amp = softplusf(r2);
    float s0 = red[t*7+3], s1 = red[t*7+4], s2 = red[t*7+5], s3 = red[t*7+6];
    float m = fmaxf(fmaxf(s0,s1), fmaxf(s2,s3));
    float e0 = expf(s0-m), e1 = expf(s1-m), e2 = expf(s2-m), e3 = expf(s3-m);
    float inv = 1.f/(e0+e1+e2+e3);
    float w0 = e0*inv, w1 = e1*inv, w2 = e2*inv, w3 = e3*inv;
    musL[t] = mu; sigL[t] = sig; ampL[t] = amp;
    shwL[t*4+0] = w0; shwL[t*4+1] = w1; shwL[t*4+2] = w2; shwL[t*4+3] = w3;
    mu_o[b*Kn + t] = mu;
    float ent = 0.f, sw;
    sw = fmaxf(w0,1e-8f); ent += sw*logf(sw);
    sw = fmaxf(w1,1e-8f); ent += sw*logf(sw);
    sw = fmaxf(w2,1e-8f); ent += sw*logf(sw);
    sw = fmaxf(w3,1e-8f); ent += sw*logf(sw);
    entS[t] = ent;
  }
  __syncthreads();
  // kappa for all (k,h)
  for (int p = t; p < Kn*Hn; p += 128){
    int k = p/Hn, h = p - k*Hn;
    float mu = musL[k], sig = sigL[k], amp = ampL[k];
    float w0 = shwL[k*4+0], w1 = shwL[k*4+1], w2 = shwL[k*4+2], w3 = shwL[k*4+3];
    float tt = (h + 0.5f)/(float)Hn;
    float z  = (tt - mu)/sig;
    float az = fabsf(z);
    float b0 = expf(-0.5f*z*z);
    float b1 = expf(-az);
    float b2 = fmaxf(1.f-az, 0.f);
    float zc = fminf(fmaxf(z,-1.f),1.f);
    float b3 = (az <= 1.f) ? 0.5f*(1.f+cosf(3.14159265358979f*zc)) : 0.f;
    kapS[p] = amp*(w0*b0 + w1*b1 + w2*b2 + w3*b3);
  }
  __syncthreads();
  // store transposed kappa [b][h][k] for k_kemb's scalar loads
  for (int q = t; q < Kn*Hn; q += 128){
    int h = q >> 4, k = q & 15;
    kapT[((size_t)b*Hn + h)*Kn + k] = kapS[k*Hn + h];
  }
  // row masses
  {
    int k = t >> 3, j8 = t & 7;
    float s = 0.f;
    for (int h = j8; h < Hn; h += 8) s += kapS[k*Hn + h];
    red[t] = s;
  }
  __syncthreads();
  if (t < Kn){
    float s = 0.f;
    for (int j = 0; j < 8; ++j) s += red[t*8 + j];
    rrS[t] = s + 1e-6f;
  }
  __syncthreads();
  if (t == 0){
    float tot = 0.f, tv = 0.f, es = 0.f;
    for (int k = 0; k < Kn; ++k) tot += rrS[k];
    for (int k = 1; k < Kn; ++k) tv += fabsf(musL[k]-musL[k-1]);
    for (int k = 0; k < Kn; ++k) es += entS[k];
    totS = tot; part_tv[b] = tv; part_ent[b] = es;
  }
  __syncthreads();
  if (t < Kn) rr_o[b*Kn + t] = rrS[t]/totS;
  // ytir
  for (int h = t; h < Hn; h += 128){
    float s = 0.f;
    #pragma unroll
    for (int k = 0; k < Kn; ++k) s += kapS[k*Hn + h];
    ytirs[b*Hn + h] = s;
  }
}

// ---------- 2. k_emb = kappa @ W_kemb + b, l2-normalized (scalar loads of kapT) ----------
__global__ __launch_bounds__(128) void k_kemb(const float* __restrict__ kapT,
    const float* __restrict__ W, const float* __restrict__ bb, float* __restrict__ kn_o){
  int b = blockIdx.x, e = threadIdx.x;  // 128 = EMB
  float acc[Kn];
  float bv = bb[e];
  #pragma unroll
  for (int k = 0; k < Kn; ++k) acc[k] = bv;
  const float* kb = kapT + (size_t)b*Hn*Kn;
  for (int h = 0; h < Hn; ++h){
    float wv = W[h*EMBn + e];
    const float4* kr = (const float4*)(kb + h*Kn);   // wave-uniform -> s_load
    float4 c0 = kr[0], c1 = kr[1], c2 = kr[2], c3 = kr[3];
    acc[0]  += c0.x*wv; acc[1]  += c0.y*wv; acc[2]  += c0.z*wv; acc[3]  += c0.w*wv;
    acc[4]  += c1.x*wv; acc[5]  += c1.y*wv; acc[6]  += c1.z*wv; acc[7]  += c1.w*wv;
    acc[8]  += c2.x*wv; acc[9]  += c2.y*wv; acc[10] += c2.z*wv; acc[11] += c2.w*wv;
    acc[12] += c3.x*wv; acc[13] += c3.y*wv; acc[14] += c3.z*wv; acc[15] += c3.w*wv;
  }
  __shared__ float kS[EMBn*Kn];
  #pragma unroll
  for (int k = 0; k < Kn; ++k) kS[e*Kn + k] = acc[k];
  __syncthreads();
  __shared__ float r2[8*Kn];
  {
    int k = e & 15, g = e >> 4;
    float s = 0.f;
    for (int i = g; i < EMBn; i += 8){ float v = kS[i*Kn + k]; s += v*v; }
    r2[g*Kn + k] = s;
  }
  __syncthreads();
  __shared__ float invS[Kn];
  if (e < Kn){
    float s = 0.f;
    for (int g = 0; g < 8; ++g) s += r2[g*Kn + e];
    invS[e] = 1.f/(sqrtf(s) + 1e-8f);
  }
  __syncthreads();
  #pragma unroll
  for (int k = 0; k < Kn; ++k)
    kn_o[((size_t)(b*Kn + k))*EMBn + e] = acc[k]*invS[k];
}

// ---------- 3. precombine W_fp into Wa/Wb/Wc, packed [d/4][e][4] ----------
__global__ void k_wprep(const float* __restrict__ W, float* __restrict__ Wa,
                        float* __restrict__ Wb, float* __restrict__ Wc){
  int tid = blockIdx.x*256 + threadIdx.x;   // 32768
  int d = tid >> 7, e = tid & 127;
  float w0 = W[d*EMBn + e];
  float w1 = W[(Dn + d)*EMBn + e];
  float w2 = W[(2*Dn + d)*EMBn + e];
  int o = (d >> 2)*512 + e*4 + (d & 3);
  Wa[o] = w0 + w1 + w2;
  Wb[o] = w1 + 2.f*w2;
  Wc[o] = w2;
}

// ---------- 4. gate MLP (tsg fused; text/vproj via scalar loads) ----------
__global__ __launch_bounds__(512) void k_gate(const float* __restrict__ enc,
    const float* __restrict__ text, const float* __restrict__ vp,
    const float* __restrict__ W1, const float* __restrict__ b1,
    const float* __restrict__ W2, const float* __restrict__ b2,
    float* __restrict__ gate_o){
  int b = blockIdx.x, t = threadIdx.x;
  __shared__ float4 redS[512];
  __shared__ float tsgS[Dn];
  __shared__ float hidS[512];
  __shared__ float l2S[Dn];
  int d4 = t & 63, part = t >> 6;
  const float4* e4 = (const float4*)(enc + (size_t)b*Ln*Dn);
  float4 s4 = make_float4(0.f,0.f,0.f,0.f);
  for (int l = part; l < Ln; l += 8){
    float4 v = e4[(size_t)l*64 + d4];
    s4.x += v.x; s4.y += v.y; s4.z += v.z; s4.w += v.w;
  }
  redS[t] = s4;
  __syncthreads();
  if (part == 0){
    float4 o = make_float4(0.f,0.f,0.f,0.f);
    for (int p = 0; p < 8; ++p){
      float4 v = redS[p*64 + d4];
      o.x += v.x; o.y += v.y; o.z += v.z; o.w += v.w;
    }
    const float inv = 1.f/(float)Ln;
    o.x *= inv; o.y *= inv; o.z *= inv; o.w *= inv;
    ((float4*)tsgS)[d4] = o;
  }
  __syncthreads();
  // layer 1
  float s = b1[t];
  for (int i = 0; i < Dn; i += 4){
    float4 x = ((const float4*)tsgS)[i>>2];
    s += x.x*W1[(i+0)*512+t] + x.y*W1[(i+1)*512+t]
       + x.z*W1[(i+2)*512+t] + x.w*W1[(i+3)*512+t];
  }
  const float* tb = text + (size_t)b*TXTn;
  for (int i = 0; i < TXTn; i += 4){
    float4 x = *(const float4*)(tb + i);    // uniform -> s_load
    s += x.x*W1[(Dn+i+0)*512+t] + x.y*W1[(Dn+i+1)*512+t]
       + x.z*W1[(Dn+i+2)*512+t] + x.w*W1[(Dn+i+3)*512+t];
  }
  for (int i = 0; i < Dn; i += 4){
    float4 x = *(const float4*)(vp + i);    // uniform -> s_load
    s += x.x*W1[(Dn+TXTn+i+0)*512+t] + x.y*W1[(Dn+TXTn+i+1)*512+t]
       + x.z*W1[(Dn+TXTn+i+2)*512+t] + x.w*W1[(Dn+TXTn+i+3)*512+t];
  }
  hidS[t] = fmaxf(s, 0.f);
  __syncthreads();
  // layer 2, split over two halves of the hidden dim
  int d = t & 255;
  int half = __builtin_amdgcn_readfirstlane(t >> 8);
  float s2 = 0.f;
  int i0 = half*256;
  for (int i = i0; i < i0 + 256; i += 4){
    float4 hv = ((const float4*)hidS)[i>>2];
    s2 += hv.x*W2[(i+0)*Dn+d] + hv.y*W2[(i+1)*Dn+d]
        + hv.z*W2[(i+2)*Dn+d] + hv.w*W2[(i+3)*Dn+d];
  }
  if (half) l2S[d] = s2;
  __syncthreads();
  if (!half){
    float o = s2 + l2S[d] + b2[d];
    gate_o[b*Dn + d] = 1.f/(1.f + expf(-o));
  }
}

// ---------- 5. f_pos via Wa/Wb/Wc clamp formula; y via scalar loads; finv fused ----------
__global__ __launch_bounds__(256) void k_fpos(const float* __restrict__ yf,
    const float* __restrict__ Wa, const float* __restrict__ Wb, const float* __restrict__ Wc,
    const float* __restrict__ bb, float* __restrict__ fpos, float* __restrict__ finv){
  int b = blockIdx.x / NT, tile = blockIdx.x % NT;
  int t = threadIdx.x, e = t & 127;
  int rh = __builtin_amdgcn_readfirstlane(t >> 7);
  int h0 = tile*FT + rh*RT;
  const float* yb = yf + (size_t)b*Hn*Dn;
  float f[RT];
  float bv = bb[e];
  #pragma unroll
  for (int r = 0; r < RT; ++r) f[r] = bv;
  for (int dc = 0; dc < Dn; dc += 4){
    int wo = (dc >> 2)*512 + e*4;
    float4 wa = *(const float4*)(Wa + wo);
    float4 wb = *(const float4*)(Wb + wo);
    float4 wc = *(const float4*)(Wc + wo);
    const float* yd = yb + dc;
    if (h0 >= 2){
      float4 y = *(const float4*)(yd + (size_t)(h0-2)*Dn);
      f[0] += dot4(y, wc);
      y = *(const float4*)(yd + (size_t)(h0-1)*Dn);
      f[0] -= dot4(y, wb);
      f[1] += dot4(y, wc);
    } else {            // h0 == 0: clamp extras for j=0
      float4 y = *(const float4*)(yd);
      float dq = dot4(y, wc);
      f[0] += dq - dot4(y, wb);
      f[1] += dq;
    }
    #pragma unroll
    for (int r = 0; r < RT-2; ++r){
      float4 y = *(const float4*)(yd + (size_t)(h0+r)*Dn);   // uniform -> s_load_dwordx4
      f[r]   += dot4(y, wa);
      f[r+1] -= dot4(y, wb);
      f[r+2] += dot4(y, wc);
    }
    {
      float4 y = *(const float4*)(yd + (size_t)(h0+RT-2)*Dn);
      f[RT-2] += dot4(y, wa);
      f[RT-1] -= dot4(y, wb);
      y = *(const float4*)(yd + (size_t)(h0+RT-1)*Dn);
      f[RT-1] += dot4(y, wa);
    }
  }
  // store + fused row-norm
  __shared__ float prS[4][RT];
  int wave = t >> 6, lane = t & 63;
  #pragma unroll
  for (int r = 0; r < RT; ++r){
    fpos[((size_t)(b*Hn) + h0 + r)*EMBn + e] = f[r];
    float sq = f[r]*f[r];
    for (int o = 32; o; o >>= 1) sq += __shfl_down(sq, o);
    if (lane == 0) prS[wave][r] = sq;
  }
  __syncthreads();
  if (t < 2*RT){
    int g = t / RT, r = t - g*RT;
    float s = prS[g*2][r] + prS[g*2+1][r];
    finv[(size_t)b*Hn + tile*FT + g*RT + r] = 1.f/(sqrtf(s) + 1e-8f);
  }
}

// ---------- 6. MSE of gated fusion (per-block partials) ----------
__global__ void k_mse(const float* __restrict__ yres, const float* __restrict__ yfut,
                      const float* __restrict__ gate, const float* __restrict__ ytirs,
                      const float* __restrict__ Wt, const float* __restrict__ bt,
                      const float* __restrict__ vp, float* __restrict__ part_mse){
  const long long total = (long long)Bn*Hn*Dn;
  long long tid = blockIdx.x*(long long)blockDim.x + threadIdx.x;
  long long nth = gridDim.x*(long long)blockDim.x;
  float part = 0.f;
  for (long long i4 = tid; i4*4 < total; i4 += nth){
    long long base = i4*4;
    int b = (int)(base/((long long)Hn*Dn));
    int rem = (int)(base - (long long)b*Hn*Dn);
    int h = rem/Dn, d = rem - h*Dn;
    float4 yr = *(const float4*)(yres + base);
    float4 yv = *(const float4*)(yfut + base);
    float4 g  = *(const float4*)(gate + (size_t)b*Dn + d);
    float4 wt = *(const float4*)(Wt + d);
    float4 bv = *(const float4*)(bt + d);
    float4 vv = *(const float4*)(vp + d);
    float ys = ytirs[b*Hn + h];
    float yt, yh, e;
    yt = (ys*wt.x + bv.x)*vv.x; yh = yr.x + 0.5f*g.x*(yt-yr.x); e = yh-yv.x; part += e*e;
    yt = (ys*wt.y + bv.y)*vv.y; yh = yr.y + 0.5f*g.y*(yt-yr.y); e = yh-yv.y; part += e*e;
    yt = (ys*wt.z + bv.z)*vv.z; yh = yr.z + 0.5f*g.z*(yt-yr.z); e = yh-yv.z; part += e*e;
    yt = (ys*wt.w + bv.w)*vv.w; yh = yr.w + 0.5f*g.w*(yt-yr.w); e = yh-yv.w; part += e*e;
  }
  __shared__ float red[256];
  red[threadIdx.x] = part; __syncthreads();
  for (int s = 128; s > 0; s >>= 1){
    if (threadIdx.x < s) red[threadIdx.x] += red[threadIdx.x + s];
    __syncthreads();
  }
  if (threadIdx.x == 0) part_mse[blockIdx.x] = red[0];
}

// ---------- 7. per-batch: C, Sinkhorn, cot, delta-contrastive ----------
__global__ void __launch_bounds__(256)
k_sink(const float* __restrict__ kn, const float* __restrict__ fpos,
       const float* __restrict__ finv, const float* __restrict__ mu_i,
       const float* __restrict__ rr, const int* __restrict__ perm,
       float* __restrict__ part_cot, float* __restrict__ part_del){
  int b = blockIdx.x, t = threadIdx.x;  // 256 threads
  __shared__ float Cm[Kn*Hn];           // C; later aliased aggp/agg1
  __shared__ float Km[Kn*Hn];           // Kmat
  __shared__ float wT[Hn*Kn];           // transposed transport weights
  __shared__ float vS[Hn];
  __shared__ float uS[Kn], rrS[Kn], musS[Kn], rowS[Kn];
  __shared__ float red[256];
  __shared__ int permS[EMBn];
  float* aggp = Cm;
  float* agg1 = Cm + Kn*EMBn;

  if (t < EMBn) permS[t] = perm[t];
  if (t < Kn){ musS[t] = mu_i[b*Kn + t]; rrS[t] = rr[b*Kn + t]; }
  for (int h = t; h < Hn; h += 256) vS[h] = 1.f;
  __syncthreads();

  for (int p = t; p < Kn*Hn; p += 256){
    int k = p/Hn, h = p - k*Hn;
    const float4* f4 = (const float4*)(fpos + ((size_t)b*Hn + h)*EMBn);
    const float4* k4 = (const float4*)(kn   + ((size_t)b*Kn + k)*EMBn);
    float s = 0.f;
    #pragma unroll 8
    for (int i = 0; i < EMBn/4; ++i){
      float4 a = k4[i], f = f4[i];
      s += a.x*f.x + a.y*f.y + a.z*f.z + a.w*f.w;
    }
    float cs = s*finv[b*Hn + h];
    float th = (h + 0.5f)/(float)Hn;
    float c  = (1.f - cs) + 0.5f*fmaxf(musS[k] - th, 0.f);
    Cm[p] = c;
    Km[p] = expf(-20.f*c);   // 1/EPS = 20
  }
  __syncthreads();

  int wave = t >> 6, lane = t & 63;
  for (int it = 0; it < 30; ++it){
    for (int i = 0; i < 4; ++i){
      int k = wave*4 + i;
      float s = 0.f;
      for (int h = lane; h < Hn; h += 64) s += Km[k*Hn + h]*vS[h];
      for (int o = 32; o; o >>= 1) s += __shfl_down(s, o);
      if (lane == 0) uS[k] = rrS[k]/(s + 1e-9f);
    }
    __syncthreads();
    for (int h = t; h < Hn; h += 256){
      float s = 0.f;
      #pragma unroll
      for (int k = 0; k < Kn; ++k) s += Km[k*Hn + h]*uS[k];
      vS[h] = (1.f/(float)Hn)/(s + 1e-9f);
    }
    __syncthreads();
  }

  for (int i = 0; i < 4; ++i){
    int k = wave*4 + i;
    float s = 0.f;
    for (int h = lane; h < Hn; h += 64) s += Km[k*Hn + h]*vS[h];
    for (int o = 32; o; o >>= 1) s += __shfl_down(s, o);
    if (lane == 0) rowS[k] = uS[k]*s;
  }
  __syncthreads();

  // cot partial + transposed w
  float cotp = 0.f;
  for (int p = t; p < Kn*Hn; p += 256){
    int k = p/Hn, h = p - k*Hn;
    float Pi = uS[k]*Km[p]*vS[h];
    cotp += Cm[p]*Pi;
    wT[h*Kn + k] = Pi/(rowS[k] + 1e-9f);
  }
  red[t] = cotp; __syncthreads();
  for (int s = 128; s > 0; s >>= 1){ if (t < s) red[t] += red[t+s]; __syncthreads(); }
  if (t == 0) part_cot[b] = red[0];
  __syncthreads();   // Cm free; wT complete

  // agg_pos / agg_neg1 (roll(SHIFT) as shifted w-index)
  {
    int e = t & 127, kg = __builtin_amdgcn_readfirstlane(t >> 7);
    float ap[8], a1[8];
    #pragma unroll
    for (int j = 0; j < 8; ++j){ ap[j] = 0.f; a1[j] = 0.f; }
    for (int h = 0; h < Hn; ++h){
      float fv = fpos[((size_t)b*Hn + h)*EMBn + e];
      int h1 = h + SHIFT; if (h1 >= Hn) h1 -= Hn;
      float4 wA0 = *(const float4*)&wT[h *Kn + kg*8];
      float4 wA1 = *(const float4*)&wT[h *Kn + kg*8 + 4];
      float4 wB0 = *(const float4*)&wT[h1*Kn + kg*8];
      float4 wB1 = *(const float4*)&wT[h1*Kn + kg*8 + 4];
      ap[0] += wA0.x*fv; ap[1] += wA0.y*fv; ap[2] += wA0.z*fv; ap[3] += wA0.w*fv;
      ap[4] += wA1.x*fv; ap[5] += wA1.y*fv; ap[6] += wA1.z*fv; ap[7] += wA1.w*fv;
      a1[0] += wB0.x*fv; a1[1] += wB0.y*fv; a1[2] += wB0.z*fv; a1[3] += wB0.w*fv;
      a1[4] += wB1.x*fv; a1[5] += wB1.y*fv; a1[6] += wB1.z*fv; a1[7] += wB1.w*fv;
    }
    #pragma unroll
    for (int j = 0; j < 8; ++j){
      int k = kg*8 + j;
      aggp[k*EMBn + e] = ap[j];
      agg1[k*EMBn + e] = a1[j];
    }
  }
  __syncthreads();

  float dsum = 0.f;
  for (int i = 0; i < 4; ++i){
    int k = wave*4 + i;
    float sp = 0.f, s1 = 0.f, s2 = 0.f, np = 0.f, n1 = 0.f;
    for (int e = lane; e < EMBn; e += 64){
      float kne = kn[((size_t)b*Kn + k)*EMBn + e];
      float a  = aggp[k*EMBn + e];
      float c1 = agg1[k*EMBn + e];
      sp += kne*a; s1 += kne*c1;
      s2 += kne*aggp[k*EMBn + permS[e]];
      np += a*a; n1 += c1*c1;
    }
    for (int o = 32; o; o >>= 1){
      sp += __shfl_down(sp, o); s1 += __shfl_down(s1, o); s2 += __shfl_down(s2, o);
      np += __shfl_down(np, o); n1 += __shfl_down(n1, o);
    }
    if (lane == 0){
      float ip  = 1.f/(sqrtf(np) + 1e-8f);
      float i1v = 1.f/(sqrtf(n1) + 1e-8f);
      const float ti = 1.f/0.07f;
      float l0 = sp*ip*ti, l1 = s1*i1v*ti, l2 = s2*ip*ti;
      float m = fmaxf(l0, fmaxf(l1, l2));
      float lse = m + logf(expf(l0-m) + expf(l1-m) + expf(l2-m));
      dsum += (lse - l0);
    }
  }
  __syncthreads();
  if (lane == 0) red[wave] = dsum;
  __syncthreads();
  if (t == 0) part_del[b] = red[0] + red[1] + red[2] + red[3];
}

// ---------- 8. combine ----------
__global__ void k_final(const float* __restrict__ part_mse, const float* __restrict__ part_cot,
                        const float* __restrict__ part_del, const float* __restrict__ part_ent,
                        const float* __restrict__ part_tv, float* __restrict__ out){
  int t = threadIdx.x;  // 256
  __shared__ double sred[256];
  double m = 0.0;
  for (int i = t; i < MSEB; i += 256) m += (double)part_mse[i];
  double o4 = 0.0;
  if (t < Bn){
    o4 = 0.1*(double)part_cot[t] + (0.1/(double)Kn)*(double)part_del[t]
       - (0.01/(double)Kn)*(double)part_ent[t] + (0.01/(double)(Kn-1))*(double)part_tv[t];
  }
  sred[t] = m/((double)Bn*Hn*Dn) + o4/(double)Bn;
  __syncthreads();
  for (int s = 128; s > 0; s >>= 1){ if (t < s) sred[t] += sred[t+s]; __syncthreads(); }
  if (t == 0) out[0] = (float)sred[0];
}

// ---------- launch ----------
extern "C" void kernel_launch(void* const* d_in, const int* in_sizes, int n_in,
                              void* d_out, int out_size, void* d_ws, size_t ws_size,
                              hipStream_t stream) {
  const float* y_res  = (const float*)d_in[0];
  const float* text   = (const float*)d_in[1];
  const float* enc    = (const float*)d_in[2];
  const float* yfut   = (const float*)d_in[3];
  const int*   perm   = (const int*)  d_in[4];
  const float* W_t2k  = (const float*)d_in[5];
  const float* b_t2k  = (const float*)d_in[6];
  const float* W_kemb = (const float*)d_in[7];
  const float* b_kemb = (const float*)d_in[8];
  const float* W_tir  = (const float*)d_in[9];
  const float* b_tir  = (const float*)d_in[10];
  const float* vproj  = (const float*)d_in[11];
  const float* W_g1   = (const float*)d_in[12];
  const float* b_g1   = (const float*)d_in[13];
  const float* W_g2   = (const float*)d_in[14];
  const float* b_g2   = (const float*)d_in[15];
  const float* W_fp   = (const float*)d_in[16];
  const float* b_fp   = (const float*)d_in[17];

  float* F = (float*)d_ws;
  float* mu_w   = F;            // 2048
  float* rr_w   = F + 2048;     // 2048
  float* ytr_w  = F + 4096;     // 43008
  float* kapT_w = F + 47104;    // 688128 (reused for Wa/Wb/Wc after k_kemb)
  float* kn_w   = F + 735232;   // 262144
  float* gate_w = F + 997376;   // 32768
  float* fp_w   = F + 1030144;  // 5505024
  float* fi_w   = F + 6535168;  // 43008
  float* pmse_w = F + 6578176;  // 1024
  float* pcot_w = F + 6579200;  // 128
  float* pdel_w = F + 6579328;  // 128
  float* pent_w = F + 6579456;  // 128
  float* ptv_w  = F + 6579584;  // 128
  float* Wa_w = kapT_w;
  float* Wb_w = kapT_w + 32768;
  float* Wc_w = kapT_w + 65536;

  k_fused1<<<Bn, 128, 0, stream>>>(text, W_t2k, b_t2k, mu_w, kapT_w, rr_w, ytr_w, pent_w, ptv_w);
  k_kemb  <<<Bn, 128, 0, stream>>>(kapT_w, W_kemb, b_kemb, kn_w);
  k_wprep <<<128, 256, 0, stream>>>(W_fp, Wa_w, Wb_w, Wc_w);   // after k_kemb (overlays kapT)
  k_gate  <<<Bn, 512, 0, stream>>>(enc, text, vproj, W_g1, b_g1, W_g2, b_g2, gate_w);
  k_fpos  <<<Bn*NT, 256, 0, stream>>>(yfut, Wa_w, Wb_w, Wc_w, b_fp, fp_w, fi_w);
  k_mse   <<<MSEB, 256, 0, stream>>>(y_res, yfut, gate_w, ytr_w, W_tir, b_tir, vproj, pmse_w);
  k_sink  <<<Bn, 256, 0, stream>>>(kn_w, fp_w, fi_w, mu_w, rr_w, perm, pcot_w, pdel_w);
  k_final <<<1, 256, 0, stream>>>(pmse_w, pcot_w, pdel_w, pent_w, ptv_w, (float*)d_out);
}

// Round 5
// 565.912 us; speedup vs baseline: 26.5101x; 1.3826x over previous
//
#include <hip/hip_runtime.h>
#include <math.h>

#define Bn   128
#define Ln   512
#define Hn   336
#define Dn   256
#define TXTn 768
#define Kn   16
#define EMBn 128
#define SHIFT 56      // max(1, H//6)
#define MSEB 1024
#define FROWS 48      // k_fposm rows per block (336/48 = 7)
#define FTILES 7
#define ASTRIDE 776   // 768 + 8 bf16 pad (row stride in shorts; 1552 B, 2-way bank alias = free)

typedef __attribute__((ext_vector_type(8))) short short8;
typedef __attribute__((ext_vector_type(4))) float floatx4;

__device__ __forceinline__ float dot4(float4 a, float4 b){
  return a.x*b.x + a.y*b.y + a.z*b.z + a.w*b.w;
}

__device__ __forceinline__ float softplusf(float x){
  return fmaxf(x, 0.f) + log1pf(expf(-fabsf(x)));
}

__device__ __forceinline__ unsigned short f2bf(float x){  // RNE f32 -> bf16 bits
  unsigned int u = __float_as_uint(x);
  unsigned int r = (u + 0x7fffu + ((u >> 16) & 1u)) >> 16;
  return (unsigned short)r;
}

// ---------- 1. fused: text->params, kappa, rr(normalized), ytir, ent/tv partials ----------
__global__ __launch_bounds__(128) void k_fused1(
    const float* __restrict__ text, const float* __restrict__ W, const float* __restrict__ bb,
    float* __restrict__ mu_o, float* __restrict__ kapT, float* __restrict__ rr_o,
    float* __restrict__ ytirs, float* __restrict__ part_ent, float* __restrict__ part_tv){
  int b = blockIdx.x, t = threadIdx.x;
  __shared__ float kapS[Kn*Hn];
  __shared__ float musL[Kn], sigL[Kn], ampL[Kn], shwL[Kn*4], entS[Kn], rrS[Kn];
  __shared__ float red[128];
  __shared__ float totS;
  if (t < Kn*7){
    float s = bb[t];
    const float* tb = text + (size_t)b*TXTn;
    for (int i = 0; i < TXTn; i += 4){
      float4 x = *(const float4*)(tb + i);
      s += x.x*W[(i+0)*112 + t] + x.y*W[(i+1)*112 + t]
         + x.z*W[(i+2)*112 + t] + x.w*W[(i+3)*112 + t];
    }
    red[t] = s;
  }
  __syncthreads();
  if (t < Kn){
    float r0 = red[t*7+0], r1 = red[t*7+1], r2 = red[t*7+2];
    float mu  = 1.f/(1.f+expf(-r0));
    float sig = softplusf(r1)*0.15f + 1e-3f;
    float amp = softplusf(r2);
    float s0 = red[t*7+3], s1 = red[t*7+4], s2 = red[t*7+5], s3 = red[t*7+6];
    float m = fmaxf(fmaxf(s0,s1), fmaxf(s2,s3));
    float e0 = expf(s0-m), e1 = expf(s1-m), e2 = expf(s2-m), e3 = expf(s3-m);
    float inv = 1.f/(e0+e1+e2+e3);
    float w0 = e0*inv, w1 = e1*inv, w2 = e2*inv, w3 = e3*inv;
    musL[t] = mu; sigL[t] = sig; ampL[t] = amp;
    shwL[t*4+0] = w0; shwL[t*4+1] = w1; shwL[t*4+2] = w2; shwL[t*4+3] = w3;
    mu_o[b*Kn + t] = mu;
    float ent = 0.f, sw;
    sw = fmaxf(w0,1e-8f); ent += sw*logf(sw);
    sw = fmaxf(w1,1e-8f); ent += sw*logf(sw);
    sw = fmaxf(w2,1e-8f); ent += sw*logf(sw);
    sw = fmaxf(w3,1e-8f); ent += sw*logf(sw);
    entS[t] = ent;
  }
  __syncthreads();
  for (int p = t; p < Kn*Hn; p += 128){
    int k = p/Hn, h = p - k*Hn;
    float mu = musL[k], sig = sigL[k], amp = ampL[k];
    float w0 = shwL[k*4+0], w1 = shwL[k*4+1], w2 = shwL[k*4+2], w3 = shwL[k*4+3];
    float tt = (h + 0.5f)/(float)Hn;
    float z  = (tt - mu)/sig;
    float az = fabsf(z);
    float b0 = expf(-0.5f*z*z);
    float b1 = expf(-az);
    float b2 = fmaxf(1.f-az, 0.f);
    float zc = fminf(fmaxf(z,-1.f),1.f);
    float b3 = (az <= 1.f) ? 0.5f*(1.f+cosf(3.14159265358979f*zc)) : 0.f;
    kapS[p] = amp*(w0*b0 + w1*b1 + w2*b2 + w3*b3);
  }
  __syncthreads();
  for (int q = t; q < Kn*Hn; q += 128){
    int h = q >> 4, k = q & 15;
    kapT[((size_t)b*Hn + h)*Kn + k] = kapS[k*Hn + h];
  }
  {
    int k = t >> 3, j8 = t & 7;
    float s = 0.f;
    for (int h = j8; h < Hn; h += 8) s += kapS[k*Hn + h];
    red[t] = s;
  }
  __syncthreads();
  if (t < Kn){
    float s = 0.f;
    for (int j = 0; j < 8; ++j) s += red[t*8 + j];
    rrS[t] = s + 1e-6f;
  }
  __syncthreads();
  if (t == 0){
    float tot = 0.f, tv = 0.f, es = 0.f;
    for (int k = 0; k < Kn; ++k) tot += rrS[k];
    for (int k = 1; k < Kn; ++k) tv += fabsf(musL[k]-musL[k-1]);
    for (int k = 0; k < Kn; ++k) es += entS[k];
    totS = tot; part_tv[b] = tv; part_ent[b] = es;
  }
  __syncthreads();
  if (t < Kn) rr_o[b*Kn + t] = rrS[t]/totS;
  for (int h = t; h < Hn; h += 128){
    float s = 0.f;
    #pragma unroll
    for (int k = 0; k < Kn; ++k) s += kapS[k*Hn + h];
    ytirs[b*Hn + h] = s;
  }
}

// ---------- 2. k_emb = kappa @ W_kemb + b, l2-normalized ----------
__global__ __launch_bounds__(128) void k_kemb(const float* __restrict__ kapT,
    const float* __restrict__ W, const float* __restrict__ bb, float* __restrict__ kn_o){
  int b = blockIdx.x, e = threadIdx.x;  // 128 = EMB
  float acc[Kn];
  float bv = bb[e];
  #pragma unroll
  for (int k = 0; k < Kn; ++k) acc[k] = bv;
  const float* kb = kapT + (size_t)b*Hn*Kn;
  for (int h = 0; h < Hn; ++h){
    float wv = W[h*EMBn + e];
    const float4* kr = (const float4*)(kb + h*Kn);   // wave-uniform -> s_load
    float4 c0 = kr[0], c1 = kr[1], c2 = kr[2], c3 = kr[3];
    acc[0]  += c0.x*wv; acc[1]  += c0.y*wv; acc[2]  += c0.z*wv; acc[3]  += c0.w*wv;
    acc[4]  += c1.x*wv; acc[5]  += c1.y*wv; acc[6]  += c1.z*wv; acc[7]  += c1.w*wv;
    acc[8]  += c2.x*wv; acc[9]  += c2.y*wv; acc[10] += c2.z*wv; acc[11] += c2.w*wv;
    acc[12] += c3.x*wv; acc[13] += c3.y*wv; acc[14] += c3.z*wv; acc[15] += c3.w*wv;
  }
  __shared__ float kS[EMBn*Kn];
  #pragma unroll
  for (int k = 0; k < Kn; ++k) kS[e*Kn + k] = acc[k];
  __syncthreads();
  __shared__ float r2[8*Kn];
  {
    int k = e & 15, g = e >> 4;
    float s = 0.f;
    for (int i = g; i < EMBn; i += 8){ float v = kS[i*Kn + k]; s += v*v; }
    r2[g*Kn + k] = s;
  }
  __syncthreads();
  __shared__ float invS[Kn];
  if (e < Kn){
    float s = 0.f;
    for (int g = 0; g < 8; ++g) s += r2[g*Kn + e];
    invS[e] = 1.f/(sqrtf(s) + 1e-8f);
  }
  __syncthreads();
  #pragma unroll
  for (int k = 0; k < Kn; ++k)
    kn_o[((size_t)(b*Kn + k))*EMBn + e] = acc[k]*invS[k];
}

// ---------- 3. W_fp f32 [768][128] -> bf16 B-fragment-swizzled layout ----------
// B_sw[((kt*8 + c)*64 + lane)*8 + j] = bf16(W[(kt*32 + (lane>>4)*8 + j)*128 + c*16 + (lane&15)])
__global__ void k_wprep(const float* __restrict__ W, unsigned short* __restrict__ Bsw){
  int tid = blockIdx.x*256 + threadIdx.x;   // 98304 total
  int k = tid >> 7, n = tid & 127;
  int kt = k >> 5, kr = k & 31, quad = kr >> 3, j = kr & 7;
  int c = n >> 4, ln = n & 15;
  int lane = quad*16 + ln;
  int dst = ((kt*8 + c)*64 + lane)*8 + j;
  Bsw[dst] = f2bf(W[k*128 + n]);
}

// ---------- 4. gate MLP (tsg fused; text/vproj via scalar loads) ----------
__global__ __launch_bounds__(512) void k_gate(const float* __restrict__ enc,
    const float* __restrict__ text, const float* __restrict__ vp,
    const float* __restrict__ W1, const float* __restrict__ b1,
    const float* __restrict__ W2, const float* __restrict__ b2,
    float* __restrict__ gate_o){
  int b = blockIdx.x, t = threadIdx.x;
  __shared__ float4 redS[512];
  __shared__ float tsgS[Dn];
  __shared__ float hidS[512];
  __shared__ float l2S[Dn];
  int d4 = t & 63, part = t >> 6;
  const float4* e4 = (const float4*)(enc + (size_t)b*Ln*Dn);
  float4 s4 = make_float4(0.f,0.f,0.f,0.f);
  for (int l = part; l < Ln; l += 8){
    float4 v = e4[(size_t)l*64 + d4];
    s4.x += v.x; s4.y += v.y; s4.z += v.z; s4.w += v.w;
  }
  redS[t] = s4;
  __syncthreads();
  if (part == 0){
    float4 o = make_float4(0.f,0.f,0.f,0.f);
    for (int p = 0; p < 8; ++p){
      float4 v = redS[p*64 + d4];
      o.x += v.x; o.y += v.y; o.z += v.z; o.w += v.w;
    }
    const float inv = 1.f/(float)Ln;
    o.x *= inv; o.y *= inv; o.z *= inv; o.w *= inv;
    ((float4*)tsgS)[d4] = o;
  }
  __syncthreads();
  float s = b1[t];
  for (int i = 0; i < Dn; i += 4){
    float4 x = ((const float4*)tsgS)[i>>2];
    s += x.x*W1[(i+0)*512+t] + x.y*W1[(i+1)*512+t]
       + x.z*W1[(i+2)*512+t] + x.w*W1[(i+3)*512+t];
  }
  const float* tb = text + (size_t)b*TXTn;
  for (int i = 0; i < TXTn; i += 4){
    float4 x = *(const float4*)(tb + i);
    s += x.x*W1[(Dn+i+0)*512+t] + x.y*W1[(Dn+i+1)*512+t]
       + x.z*W1[(Dn+i+2)*512+t] + x.w*W1[(Dn+i+3)*512+t];
  }
  for (int i = 0; i < Dn; i += 4){
    float4 x = *(const float4*)(vp + i);
    s += x.x*W1[(Dn+TXTn+i+0)*512+t] + x.y*W1[(Dn+TXTn+i+1)*512+t]
       + x.z*W1[(Dn+TXTn+i+2)*512+t] + x.w*W1[(Dn+TXTn+i+3)*512+t];
  }
  hidS[t] = fmaxf(s, 0.f);
  __syncthreads();
  int d = t & 255;
  int half = __builtin_amdgcn_readfirstlane(t >> 8);
  float s2 = 0.f;
  int i0 = half*256;
  for (int i = i0; i < i0 + 256; i += 4){
    float4 hv = ((const float4*)hidS)[i>>2];
    s2 += hv.x*W2[(i+0)*Dn+d] + hv.y*W2[(i+1)*Dn+d]
        + hv.z*W2[(i+2)*Dn+d] + hv.w*W2[(i+3)*Dn+d];
  }
  if (half) l2S[d] = s2;
  __syncthreads();
  if (!half){
    float o = s2 + l2S[d] + b2[d];
    gate_o[b*Dn + d] = 1.f/(1.f + expf(-o));
  }
}

// ---------- 5. f_pos via bf16 MFMA: A=concat(y,d1,d2) staged in LDS, B pre-swizzled ----------
__global__ __launch_bounds__(256) void k_fposm(const float* __restrict__ yf,
    const unsigned short* __restrict__ Bsw, const float* __restrict__ bb,
    float* __restrict__ fpos, float* __restrict__ finv){
  int b = blockIdx.x / FTILES, tile = blockIdx.x % FTILES;
  int t = threadIdx.x;
  int h0 = tile*FROWS;
  __shared__ unsigned short yS[FROWS*ASTRIDE];   // 74496 B
  __shared__ float rsq[4][FROWS];
  const float* yb = yf + (size_t)b*Hn*Dn;

  // ---- stage A = [y | d1 | d2] as bf16 (row-clamped diffs) ----
  #pragma unroll
  for (int u = 0; u < 12; ++u){
    int unit = t + 256*u;            // 48 rows x 64 d4-groups
    int r = unit >> 6, d4 = unit & 63;
    int h = h0 + r;
    int hm1 = h-1 < 0 ? 0 : h-1;
    int hm2 = h-2 < 0 ? 0 : h-2;
    float4 y   = *(const float4*)(yb + (size_t)h  *Dn + d4*4);
    float4 ym1 = *(const float4*)(yb + (size_t)hm1*Dn + d4*4);
    float4 ym2 = *(const float4*)(yb + (size_t)hm2*Dn + d4*4);
    float4 d1 = make_float4(y.x-ym1.x, y.y-ym1.y, y.z-ym1.z, y.w-ym1.w);
    float4 d2 = make_float4(y.x-2.f*ym1.x+ym2.x, y.y-2.f*ym1.y+ym2.y,
                            y.z-2.f*ym1.z+ym2.z, y.w-2.f*ym1.w+ym2.w);
    union { unsigned short u16[4]; uint2 v; } p;
    unsigned short* base = &yS[r*ASTRIDE + d4*4];
    p.u16[0]=f2bf(y.x);  p.u16[1]=f2bf(y.y);  p.u16[2]=f2bf(y.z);  p.u16[3]=f2bf(y.w);
    *(uint2*)(base)        = p.v;
    p.u16[0]=f2bf(d1.x); p.u16[1]=f2bf(d1.y); p.u16[2]=f2bf(d1.z); p.u16[3]=f2bf(d1.w);
    *(uint2*)(base + 256)  = p.v;
    p.u16[0]=f2bf(d2.x); p.u16[1]=f2bf(d2.y); p.u16[2]=f2bf(d2.z); p.u16[3]=f2bf(d2.w);
    *(uint2*)(base + 512)  = p.v;
  }
  __syncthreads();

  // ---- MFMA K-loop: wave wv covers 48 rows x cols [wv*32, wv*32+32) ----
  int wv   = __builtin_amdgcn_readfirstlane(t >> 6);
  int lane = t & 63, quad = lane >> 4, ln = lane & 15;
  int c0 = wv*2;
  floatx4 acc[3][2];
  #pragma unroll
  for (int i = 0; i < 3; ++i){
    acc[i][0] = (floatx4){0.f,0.f,0.f,0.f};
    acc[i][1] = (floatx4){0.f,0.f,0.f,0.f};
  }
  #pragma unroll
  for (int kt = 0; kt < 24; ++kt){
    int aoff = kt*32 + quad*8;
    short8 a0 = *(const short8*)&yS[( 0 + ln)*ASTRIDE + aoff];
    short8 a1 = *(const short8*)&yS[(16 + ln)*ASTRIDE + aoff];
    short8 a2 = *(const short8*)&yS[(32 + ln)*ASTRIDE + aoff];
    short8 b0 = *(const short8*)&Bsw[((kt*8 + c0  )*64 + lane)*8];
    short8 b1 = *(const short8*)&Bsw[((kt*8 + c0+1)*64 + lane)*8];
    acc[0][0] = __builtin_amdgcn_mfma_f32_16x16x32_bf16(a0, b0, acc[0][0], 0, 0, 0);
    acc[0][1] = __builtin_amdgcn_mfma_f32_16x16x32_bf16(a0, b1, acc[0][1], 0, 0, 0);
    acc[1][0] = __builtin_amdgcn_mfma_f32_16x16x32_bf16(a1, b0, acc[1][0], 0, 0, 0);
    acc[1][1] = __builtin_amdgcn_mfma_f32_16x16x32_bf16(a1, b1, acc[1][1], 0, 0, 0);
    acc[2][0] = __builtin_amdgcn_mfma_f32_16x16x32_bf16(a2, b0, acc[2][0], 0, 0, 0);
    acc[2][1] = __builtin_amdgcn_mfma_f32_16x16x32_bf16(a2, b1, acc[2][1], 0, 0, 0);
  }

  // ---- epilogue: bias, store f32, fused row sum-of-squares ----
  float bias0 = bb[c0*16 + ln], bias1 = bb[(c0+1)*16 + ln];
  #pragma unroll
  for (int rt = 0; rt < 3; ++rt){
    #pragma unroll
    for (int reg = 0; reg < 4; ++reg){
      int lrow = rt*16 + quad*4 + reg;
      size_t row = (size_t)b*Hn + h0 + lrow;
      float v0 = acc[rt][0][reg] + bias0;
      float v1 = acc[rt][1][reg] + bias1;
      fpos[row*EMBn + c0*16 + ln]     = v0;
      fpos[row*EMBn + (c0+1)*16 + ln] = v1;
      float sq = v0*v0 + v1*v1;
      sq += __shfl_xor(sq, 1); sq += __shfl_xor(sq, 2);
      sq += __shfl_xor(sq, 4); sq += __shfl_xor(sq, 8);
      if (ln == 0) rsq[wv][lrow] = sq;
    }
  }
  __syncthreads();
  if (t < FROWS){
    float s = rsq[0][t] + rsq[1][t] + rsq[2][t] + rsq[3][t];
    finv[(size_t)b*Hn + h0 + t] = 1.f/(sqrtf(s) + 1e-8f);
  }
}

// ---------- 6. MSE of gated fusion (per-block partials) ----------
__global__ void k_mse(const float* __restrict__ yres, const float* __restrict__ yfut,
                      const float* __restrict__ gate, const float* __restrict__ ytirs,
                      const float* __restrict__ Wt, const float* __restrict__ bt,
                      const float* __restrict__ vp, float* __restrict__ part_mse){
  const long long total = (long long)Bn*Hn*Dn;
  long long tid = blockIdx.x*(long long)blockDim.x + threadIdx.x;
  long long nth = gridDim.x*(long long)blockDim.x;
  float part = 0.f;
  for (long long i4 = tid; i4*4 < total; i4 += nth){
    long long base = i4*4;
    int b = (int)(base/((long long)Hn*Dn));
    int rem = (int)(base - (long long)b*Hn*Dn);
    int h = rem/Dn, d = rem - h*Dn;
    float4 yr = *(const float4*)(yres + base);
    float4 yv = *(const float4*)(yfut + base);
    float4 g  = *(const float4*)(gate + (size_t)b*Dn + d);
    float4 wt = *(const float4*)(Wt + d);
    float4 bv = *(const float4*)(bt + d);
    float4 vv = *(const float4*)(vp + d);
    float ys = ytirs[b*Hn + h];
    float yt, yh, e;
    yt = (ys*wt.x + bv.x)*vv.x; yh = yr.x + 0.5f*g.x*(yt-yr.x); e = yh-yv.x; part += e*e;
    yt = (ys*wt.y + bv.y)*vv.y; yh = yr.y + 0.5f*g.y*(yt-yr.y); e = yh-yv.y; part += e*e;
    yt = (ys*wt.z + bv.z)*vv.z; yh = yr.z + 0.5f*g.z*(yt-yr.z); e = yh-yv.z; part += e*e;
    yt = (ys*wt.w + bv.w)*vv.w; yh = yr.w + 0.5f*g.w*(yt-yr.w); e = yh-yv.w; part += e*e;
  }
  __shared__ float red[256];
  red[threadIdx.x] = part; __syncthreads();
  for (int s = 128; s > 0; s >>= 1){
    if (threadIdx.x < s) red[threadIdx.x] += red[threadIdx.x + s];
    __syncthreads();
  }
  if (threadIdx.x == 0) part_mse[blockIdx.x] = red[0];
}

// ---------- 7. per-batch: C, Sinkhorn, cot, delta-contrastive ----------
__global__ void __launch_bounds__(256)
k_sink(const float* __restrict__ kn, const float* __restrict__ fpos,
       const float* __restrict__ finv, const float* __restrict__ mu_i,
       const float* __restrict__ rr, const int* __restrict__ perm,
       float* __restrict__ part_cot, float* __restrict__ part_del){
  int b = blockIdx.x, t = threadIdx.x;  // 256 threads
  __shared__ float Cm[Kn*Hn];           // C; later aliased aggp/agg1
  __shared__ float Km[Kn*Hn];           // Kmat
  __shared__ float wT[Hn*Kn];           // transposed transport weights
  __shared__ float vS[Hn];
  __shared__ float uS[Kn], rrS[Kn], musS[Kn], rowS[Kn];
  __shared__ float red[256];
  __shared__ int permS[EMBn];
  float* aggp = Cm;
  float* agg1 = Cm + Kn*EMBn;

  if (t < EMBn) permS[t] = perm[t];
  if (t < Kn){ musS[t] = mu_i[b*Kn + t]; rrS[t] = rr[b*Kn + t]; }
  for (int h = t; h < Hn; h += 256) vS[h] = 1.f;
  __syncthreads();

  for (int p = t; p < Kn*Hn; p += 256){
    int k = p/Hn, h = p - k*Hn;
    const float4* f4 = (const float4*)(fpos + ((size_t)b*Hn + h)*EMBn);
    const float4* k4 = (const float4*)(kn   + ((size_t)b*Kn + k)*EMBn);
    float s = 0.f;
    #pragma unroll 8
    for (int i = 0; i < EMBn/4; ++i){
      float4 a = k4[i], f = f4[i];
      s += a.x*f.x + a.y*f.y + a.z*f.z + a.w*f.w;
    }
    float cs = s*finv[b*Hn + h];
    float th = (h + 0.5f)/(float)Hn;
    float c  = (1.f - cs) + 0.5f*fmaxf(musS[k] - th, 0.f);
    Cm[p] = c;
    Km[p] = expf(-20.f*c);   // 1/EPS = 20
  }
  __syncthreads();

  int wave = t >> 6, lane = t & 63;
  for (int it = 0; it < 30; ++it){
    for (int i = 0; i < 4; ++i){
      int k = wave*4 + i;
      float s = 0.f;
      for (int h = lane; h < Hn; h += 64) s += Km[k*Hn + h]*vS[h];
      for (int o = 32; o; o >>= 1) s += __shfl_down(s, o);
      if (lane == 0) uS[k] = rrS[k]/(s + 1e-9f);
    }
    __syncthreads();
    for (int h = t; h < Hn; h += 256){
      float s = 0.f;
      #pragma unroll
      for (int k = 0; k < Kn; ++k) s += Km[k*Hn + h]*uS[k];
      vS[h] = (1.f/(float)Hn)/(s + 1e-9f);
    }
    __syncthreads();
  }

  for (int i = 0; i < 4; ++i){
    int k = wave*4 + i;
    float s = 0.f;
    for (int h = lane; h < Hn; h += 64) s += Km[k*Hn + h]*vS[h];
    for (int o = 32; o; o >>= 1) s += __shfl_down(s, o);
    if (lane == 0) rowS[k] = uS[k]*s;
  }
  __syncthreads();

  float cotp = 0.f;
  for (int p = t; p < Kn*Hn; p += 256){
    int k = p/Hn, h = p - k*Hn;
    float Pi = uS[k]*Km[p]*vS[h];
    cotp += Cm[p]*Pi;
    wT[h*Kn + k] = Pi/(rowS[k] + 1e-9f);
  }
  red[t] = cotp; __syncthreads();
  for (int s = 128; s > 0; s >>= 1){ if (t < s) red[t] += red[t+s]; __syncthreads(); }
  if (t == 0) part_cot[b] = red[0];
  __syncthreads();   // Cm free; wT complete

  {
    int e = t & 127, kg = __builtin_amdgcn_readfirstlane(t >> 7);
    float ap[8], a1[8];
    #pragma unroll
    for (int j = 0; j < 8; ++j){ ap[j] = 0.f; a1[j] = 0.f; }
    for (int h = 0; h < Hn; ++h){
      float fv = fpos[((size_t)b*Hn + h)*EMBn + e];
      int h1 = h + SHIFT; if (h1 >= Hn) h1 -= Hn;
      float4 wA0 = *(const float4*)&wT[h *Kn + kg*8];
      float4 wA1 = *(const float4*)&wT[h *Kn + kg*8 + 4];
      float4 wB0 = *(const float4*)&wT[h1*Kn + kg*8];
      float4 wB1 = *(const float4*)&wT[h1*Kn + kg*8 + 4];
      ap[0] += wA0.x*fv; ap[1] += wA0.y*fv; ap[2] += wA0.z*fv; ap[3] += wA0.w*fv;
      ap[4] += wA1.x*fv; ap[5] += wA1.y*fv; ap[6] += wA1.z*fv; ap[7] += wA1.w*fv;
      a1[0] += wB0.x*fv; a1[1] += wB0.y*fv; a1[2] += wB0.z*fv; a1[3] += wB0.w*fv;
      a1[4] += wB1.x*fv; a1[5] += wB1.y*fv; a1[6] += wB1.z*fv; a1[7] += wB1.w*fv;
    }
    #pragma unroll
    for (int j = 0; j < 8; ++j){
      int k = kg*8 + j;
      aggp[k*EMBn + e] = ap[j];
      agg1[k*EMBn + e] = a1[j];
    }
  }
  __syncthreads();

  float dsum = 0.f;
  for (int i = 0; i < 4; ++i){
    int k = wave*4 + i;
    float sp = 0.f, s1 = 0.f, s2 = 0.f, np = 0.f, n1 = 0.f;
    for (int e = lane; e < EMBn; e += 64){
      float kne = kn[((size_t)b*Kn + k)*EMBn + e];
      float a  = aggp[k*EMBn + e];
      float c1 = agg1[k*EMBn + e];
      sp += kne*a; s1 += kne*c1;
      s2 += kne*aggp[k*EMBn + permS[e]];
      np += a*a; n1 += c1*c1;
    }
    for (int o = 32; o; o >>= 1){
      sp += __shfl_down(sp, o); s1 += __shfl_down(s1, o); s2 += __shfl_down(s2, o);
      np += __shfl_down(np, o); n1 += __shfl_down(n1, o);
    }
    if (lane == 0){
      float ip  = 1.f/(sqrtf(np) + 1e-8f);
      float i1v = 1.f/(sqrtf(n1) + 1e-8f);
      const float ti = 1.f/0.07f;
      float l0 = sp*ip*ti, l1 = s1*i1v*ti, l2 = s2*ip*ti;
      float m = fmaxf(l0, fmaxf(l1, l2));
      float lse = m + logf(expf(l0-m) + expf(l1-m) + expf(l2-m));
      dsum += (lse - l0);
    }
  }
  __syncthreads();
  if (lane == 0) red[wave] = dsum;
  __syncthreads();
  if (t == 0) part_del[b] = red[0] + red[1] + red[2] + red[3];
}

// ---------- 8. combine ----------
__global__ void k_final(const float* __restrict__ part_mse, const float* __restrict__ part_cot,
                        const float* __restrict__ part_del, const float* __restrict__ part_ent,
                        const float* __restrict__ part_tv, float* __restrict__ out){
  int t = threadIdx.x;  // 256
  __shared__ double sred[256];
  double m = 0.0;
  for (int i = t; i < MSEB; i += 256) m += (double)part_mse[i];
  double o4 = 0.0;
  if (t < Bn){
    o4 = 0.1*(double)part_cot[t] + (0.1/(double)Kn)*(double)part_del[t]
       - (0.01/(double)Kn)*(double)part_ent[t] + (0.01/(double)(Kn-1))*(double)part_tv[t];
  }
  sred[t] = m/((double)Bn*Hn*Dn) + o4/(double)Bn;
  __syncthreads();
  for (int s = 128; s > 0; s >>= 1){ if (t < s) sred[t] += sred[t+s]; __syncthreads(); }
  if (t == 0) out[0] = (float)sred[0];
}

// ---------- launch ----------
extern "C" void kernel_launch(void* const* d_in, const int* in_sizes, int n_in,
                              void* d_out, int out_size, void* d_ws, size_t ws_size,
                              hipStream_t stream) {
  const float* y_res  = (const float*)d_in[0];
  const float* text   = (const float*)d_in[1];
  const float* enc    = (const float*)d_in[2];
  const float* yfut   = (const float*)d_in[3];
  const int*   perm   = (const int*)  d_in[4];
  const float* W_t2k  = (const float*)d_in[5];
  const float* b_t2k  = (const float*)d_in[6];
  const float* W_kemb = (const float*)d_in[7];
  const float* b_kemb = (const float*)d_in[8];
  const float* W_tir  = (const float*)d_in[9];
  const float* b_tir  = (const float*)d_in[10];
  const float* vproj  = (const float*)d_in[11];
  const float* W_g1   = (const float*)d_in[12];
  const float* b_g1   = (const float*)d_in[13];
  const float* W_g2   = (const float*)d_in[14];
  const float* b_g2   = (const float*)d_in[15];
  const float* W_fp   = (const float*)d_in[16];
  const float* b_fp   = (const float*)d_in[17];

  float* F = (float*)d_ws;
  float* mu_w   = F;            // 2048
  float* rr_w   = F + 2048;     // 2048
  float* ytr_w  = F + 4096;     // 43008
  float* kapT_w = F + 47104;    // 688128 (reused for Bsw after k_kemb)
  float* kn_w   = F + 735232;   // 262144
  float* gate_w = F + 997376;   // 32768
  float* fp_w   = F + 1030144;  // 5505024
  float* fi_w   = F + 6535168;  // 43008
  float* pmse_w = F + 6578176;  // 1024
  float* pcot_w = F + 6579200;  // 128
  float* pdel_w = F + 6579328;  // 128
  float* pent_w = F + 6579456;  // 128
  float* ptv_w  = F + 6579584;  // 128
  unsigned short* Bsw_w = (unsigned short*)kapT_w;  // 98304 shorts = 192 KB

  k_fused1<<<Bn, 128, 0, stream>>>(text, W_t2k, b_t2k, mu_w, kapT_w, rr_w, ytr_w, pent_w, ptv_w);
  k_kemb  <<<Bn, 128, 0, stream>>>(kapT_w, W_kemb, b_kemb, kn_w);
  k_wprep <<<384, 256, 0, stream>>>(W_fp, Bsw_w);   // after k_kemb (overlays kapT)
  k_gate  <<<Bn, 512, 0, stream>>>(enc, text, vproj, W_g1, b_g1, W_g2, b_g2, gate_w);
  k_fposm <<<Bn*FTILES, 256, 0, stream>>>(yfut, Bsw_w, b_fp, fp_w, fi_w);
  k_mse   <<<MSEB, 256, 0, stream>>>(y_res, yfut, gate_w, ytr_w, W_tir, b_tir, vproj, pmse_w);
  k_sink  <<<Bn, 256, 0, stream>>>(kn_w, fp_w, fi_w, mu_w, rr_w, perm, pcot_w, pdel_w);
  k_final <<<1, 256, 0, stream>>>(pmse_w, pcot_w, pdel_w, pent_w, ptv_w, (float*)d_out);
}

// Round 6
// 500.596 us; speedup vs baseline: 29.9690x; 1.1305x over previous
//
#include <hip/hip_runtime.h>
#include <math.h>

#define Bn   128
#define Ln   512
#define Hn   336
#define Dn   256
#define TXTn 768
#define Kn   16
#define EMBn 128
#define SHIFT 56      // max(1, H//6)
#define MSEB 1024
#define FROWS 48      // k_fposm rows per block (336/48 = 7)
#define FTILES 7
#define ASTRIDE 776   // 768 + 8 bf16 pad

typedef __attribute__((ext_vector_type(8))) short short8;
typedef __attribute__((ext_vector_type(4))) float floatx4;

__device__ __forceinline__ float dot4(float4 a, float4 b){
  return a.x*b.x + a.y*b.y + a.z*b.z + a.w*b.w;
}
__device__ __forceinline__ float softplusf(float x){
  return fmaxf(x, 0.f) + log1pf(expf(-fabsf(x)));
}
__device__ __forceinline__ unsigned short f2bf(float x){  // RNE f32 -> bf16 bits
  unsigned int u = __float_as_uint(x);
  unsigned int r = (u + 0x7fffu + ((u >> 16) & 1u)) >> 16;
  return (unsigned short)r;
}
__device__ __forceinline__ float rcpf(float x){ return __builtin_amdgcn_rcpf(x); }
__device__ __forceinline__ float wsum(float x){
  x += __shfl_xor(x, 1);  x += __shfl_xor(x, 2);  x += __shfl_xor(x, 4);
  x += __shfl_xor(x, 8);  x += __shfl_xor(x, 16); x += __shfl_xor(x, 32);
  return x;
}

// ---------- 1. fused: text->params, kappa, rr(normalized), ytir, ent/tv partials ----------
__global__ __launch_bounds__(128) void k_fused1(
    const float* __restrict__ text, const float* __restrict__ W, const float* __restrict__ bb,
    float* __restrict__ mu_o, float* __restrict__ kapT, float* __restrict__ rr_o,
    float* __restrict__ ytirs, float* __restrict__ part_ent, float* __restrict__ part_tv){
  int b = blockIdx.x, t = threadIdx.x;
  __shared__ float kapS[Kn*Hn];
  __shared__ float musL[Kn], sigL[Kn], ampL[Kn], shwL[Kn*4], entS[Kn], rrS[Kn];
  __shared__ float red[128];
  __shared__ float totS;
  if (t < Kn*7){
    float s = bb[t];
    const float* tb = text + (size_t)b*TXTn;
    for (int i = 0; i < TXTn; i += 4){
      float4 x = *(const float4*)(tb + i);
      s += x.x*W[(i+0)*112 + t] + x.y*W[(i+1)*112 + t]
         + x.z*W[(i+2)*112 + t] + x.w*W[(i+3)*112 + t];
    }
    red[t] = s;
  }
  __syncthreads();
  if (t < Kn){
    float r0 = red[t*7+0], r1 = red[t*7+1], r2 = red[t*7+2];
    float mu  = 1.f/(1.f+expf(-r0));
    float sig = softplusf(r1)*0.15f + 1e-3f;
    float amp = softplusf(r2);
    float s0 = red[t*7+3], s1 = red[t*7+4], s2 = red[t*7+5], s3 = red[t*7+6];
    float m = fmaxf(fmaxf(s0,s1), fmaxf(s2,s3));
    float e0 = expf(s0-m), e1 = expf(s1-m), e2 = expf(s2-m), e3 = expf(s3-m);
    float inv = 1.f/(e0+e1+e2+e3);
    float w0 = e0*inv, w1 = e1*inv, w2 = e2*inv, w3 = e3*inv;
    musL[t] = mu; sigL[t] = sig; ampL[t] = amp;
    shwL[t*4+0] = w0; shwL[t*4+1] = w1; shwL[t*4+2] = w2; shwL[t*4+3] = w3;
    mu_o[b*Kn + t] = mu;
    float ent = 0.f, sw;
    sw = fmaxf(w0,1e-8f); ent += sw*logf(sw);
    sw = fmaxf(w1,1e-8f); ent += sw*logf(sw);
    sw = fmaxf(w2,1e-8f); ent += sw*logf(sw);
    sw = fmaxf(w3,1e-8f); ent += sw*logf(sw);
    entS[t] = ent;
  }
  __syncthreads();
  for (int p = t; p < Kn*Hn; p += 128){
    int k = p/Hn, h = p - k*Hn;
    float mu = musL[k], sig = sigL[k], amp = ampL[k];
    float w0 = shwL[k*4+0], w1 = shwL[k*4+1], w2 = shwL[k*4+2], w3 = shwL[k*4+3];
    float tt = (h + 0.5f)/(float)Hn;
    float z  = (tt - mu)/sig;
    float az = fabsf(z);
    float b0 = expf(-0.5f*z*z);
    float b1 = expf(-az);
    float b2 = fmaxf(1.f-az, 0.f);
    float zc = fminf(fmaxf(z,-1.f),1.f);
    float b3 = (az <= 1.f) ? 0.5f*(1.f+cosf(3.14159265358979f*zc)) : 0.f;
    kapS[p] = amp*(w0*b0 + w1*b1 + w2*b2 + w3*b3);
  }
  __syncthreads();
  for (int q = t; q < Kn*Hn; q += 128){
    int h = q >> 4, k = q & 15;
    kapT[((size_t)b*Hn + h)*Kn + k] = kapS[k*Hn + h];
  }
  {
    int k = t >> 3, j8 = t & 7;
    float s = 0.f;
    for (int h = j8; h < Hn; h += 8) s += kapS[k*Hn + h];
    red[t] = s;
  }
  __syncthreads();
  if (t < Kn){
    float s = 0.f;
    for (int j = 0; j < 8; ++j) s += red[t*8 + j];
    rrS[t] = s + 1e-6f;
  }
  __syncthreads();
  if (t == 0){
    float tot = 0.f, tv = 0.f, es = 0.f;
    for (int k = 0; k < Kn; ++k) tot += rrS[k];
    for (int k = 1; k < Kn; ++k) tv += fabsf(musL[k]-musL[k-1]);
    for (int k = 0; k < Kn; ++k) es += entS[k];
    totS = tot; part_tv[b] = tv; part_ent[b] = es;
  }
  __syncthreads();
  if (t < Kn) rr_o[b*Kn + t] = rrS[t]/totS;
  for (int h = t; h < Hn; h += 128){
    float s = 0.f;
    #pragma unroll
    for (int k = 0; k < Kn; ++k) s += kapS[k*Hn + h];
    ytirs[b*Hn + h] = s;
  }
}

// ---------- 2. k_emb = kappa @ W_kemb + b, l2-normalized ----------
__global__ __launch_bounds__(128) void k_kemb(const float* __restrict__ kapT,
    const float* __restrict__ W, const float* __restrict__ bb, float* __restrict__ kn_o){
  int b = blockIdx.x, e = threadIdx.x;  // 128 = EMB
  float acc[Kn];
  float bv = bb[e];
  #pragma unroll
  for (int k = 0; k < Kn; ++k) acc[k] = bv;
  const float* kb = kapT + (size_t)b*Hn*Kn;
  for (int h = 0; h < Hn; ++h){
    float wv = W[h*EMBn + e];
    const float4* kr = (const float4*)(kb + h*Kn);   // wave-uniform -> s_load
    float4 c0 = kr[0], c1 = kr[1], c2 = kr[2], c3 = kr[3];
    acc[0]  += c0.x*wv; acc[1]  += c0.y*wv; acc[2]  += c0.z*wv; acc[3]  += c0.w*wv;
    acc[4]  += c1.x*wv; acc[5]  += c1.y*wv; acc[6]  += c1.z*wv; acc[7]  += c1.w*wv;
    acc[8]  += c2.x*wv; acc[9]  += c2.y*wv; acc[10] += c2.z*wv; acc[11] += c2.w*wv;
    acc[12] += c3.x*wv; acc[13] += c3.y*wv; acc[14] += c3.z*wv; acc[15] += c3.w*wv;
  }
  __shared__ float kS[EMBn*Kn];
  #pragma unroll
  for (int k = 0; k < Kn; ++k) kS[e*Kn + k] = acc[k];
  __syncthreads();
  __shared__ float r2[8*Kn];
  {
    int k = e & 15, g = e >> 4;
    float s = 0.f;
    for (int i = g; i < EMBn; i += 8){ float v = kS[i*Kn + k]; s += v*v; }
    r2[g*Kn + k] = s;
  }
  __syncthreads();
  __shared__ float invS[Kn];
  if (e < Kn){
    float s = 0.f;
    for (int g = 0; g < 8; ++g) s += r2[g*Kn + e];
    invS[e] = 1.f/(sqrtf(s) + 1e-8f);
  }
  __syncthreads();
  #pragma unroll
  for (int k = 0; k < Kn; ++k)
    kn_o[((size_t)(b*Kn + k))*EMBn + e] = acc[k]*invS[k];
}

// ---------- 3. W_fp f32 [768][128] -> bf16 B-fragment-swizzled layout ----------
__global__ void k_wprep(const float* __restrict__ W, unsigned short* __restrict__ Bsw){
  int tid = blockIdx.x*256 + threadIdx.x;   // 98304 total
  int k = tid >> 7, n = tid & 127;
  int kt = k >> 5, kr = k & 31, quad = kr >> 3, j = kr & 7;
  int c = n >> 4, ln = n & 15;
  int lane = quad*16 + ln;
  int dst = ((kt*8 + c)*64 + lane)*8 + j;
  Bsw[dst] = f2bf(W[k*128 + n]);
}

// ---------- 4. gate MLP ----------
__global__ __launch_bounds__(512) void k_gate(const float* __restrict__ enc,
    const float* __restrict__ text, const float* __restrict__ vp,
    const float* __restrict__ W1, const float* __restrict__ b1,
    const float* __restrict__ W2, const float* __restrict__ b2,
    float* __restrict__ gate_o){
  int b = blockIdx.x, t = threadIdx.x;
  __shared__ float4 redS[512];
  __shared__ float tsgS[Dn];
  __shared__ float hidS[512];
  __shared__ float l2S[Dn];
  int d4 = t & 63, part = t >> 6;
  const float4* e4 = (const float4*)(enc + (size_t)b*Ln*Dn);
  float4 s4 = make_float4(0.f,0.f,0.f,0.f);
  for (int l = part; l < Ln; l += 8){
    float4 v = e4[(size_t)l*64 + d4];
    s4.x += v.x; s4.y += v.y; s4.z += v.z; s4.w += v.w;
  }
  redS[t] = s4;
  __syncthreads();
  if (part == 0){
    float4 o = make_float4(0.f,0.f,0.f,0.f);
    for (int p = 0; p < 8; ++p){
      float4 v = redS[p*64 + d4];
      o.x += v.x; o.y += v.y; o.z += v.z; o.w += v.w;
    }
    const float inv = 1.f/(float)Ln;
    o.x *= inv; o.y *= inv; o.z *= inv; o.w *= inv;
    ((float4*)tsgS)[d4] = o;
  }
  __syncthreads();
  float s = b1[t];
  for (int i = 0; i < Dn; i += 4){
    float4 x = ((const float4*)tsgS)[i>>2];
    s += x.x*W1[(i+0)*512+t] + x.y*W1[(i+1)*512+t]
       + x.z*W1[(i+2)*512+t] + x.w*W1[(i+3)*512+t];
  }
  const float* tb = text + (size_t)b*TXTn;
  for (int i = 0; i < TXTn; i += 4){
    float4 x = *(const float4*)(tb + i);
    s += x.x*W1[(Dn+i+0)*512+t] + x.y*W1[(Dn+i+1)*512+t]
       + x.z*W1[(Dn+i+2)*512+t] + x.w*W1[(Dn+i+3)*512+t];
  }
  for (int i = 0; i < Dn; i += 4){
    float4 x = *(const float4*)(vp + i);
    s += x.x*W1[(Dn+TXTn+i+0)*512+t] + x.y*W1[(Dn+TXTn+i+1)*512+t]
       + x.z*W1[(Dn+TXTn+i+2)*512+t] + x.w*W1[(Dn+TXTn+i+3)*512+t];
  }
  hidS[t] = fmaxf(s, 0.f);
  __syncthreads();
  int d = t & 255;
  int half = __builtin_amdgcn_readfirstlane(t >> 8);
  float s2 = 0.f;
  int i0 = half*256;
  for (int i = i0; i < i0 + 256; i += 4){
    float4 hv = ((const float4*)hidS)[i>>2];
    s2 += hv.x*W2[(i+0)*Dn+d] + hv.y*W2[(i+1)*Dn+d]
        + hv.z*W2[(i+2)*Dn+d] + hv.w*W2[(i+3)*Dn+d];
  }
  if (half) l2S[d] = s2;
  __syncthreads();
  if (!half){
    float o = s2 + l2S[d] + b2[d];
    gate_o[b*Dn + d] = 1.f/(1.f + expf(-o));
  }
}

// ---------- 5. f_pos via bf16 MFMA ----------
__global__ __launch_bounds__(256) void k_fposm(const float* __restrict__ yf,
    const unsigned short* __restrict__ Bsw, const float* __restrict__ bb,
    float* __restrict__ fpos, float* __restrict__ finv){
  int b = blockIdx.x / FTILES, tile = blockIdx.x % FTILES;
  int t = threadIdx.x;
  int h0 = tile*FROWS;
  __shared__ unsigned short yS[FROWS*ASTRIDE];
  __shared__ float rsq[4][FROWS];
  const float* yb = yf + (size_t)b*Hn*Dn;

  #pragma unroll
  for (int u = 0; u < 12; ++u){
    int unit = t + 256*u;
    int r = unit >> 6, d4 = unit & 63;
    int h = h0 + r;
    int hm1 = h-1 < 0 ? 0 : h-1;
    int hm2 = h-2 < 0 ? 0 : h-2;
    float4 y   = *(const float4*)(yb + (size_t)h  *Dn + d4*4);
    float4 ym1 = *(const float4*)(yb + (size_t)hm1*Dn + d4*4);
    float4 ym2 = *(const float4*)(yb + (size_t)hm2*Dn + d4*4);
    float4 d1 = make_float4(y.x-ym1.x, y.y-ym1.y, y.z-ym1.z, y.w-ym1.w);
    float4 d2 = make_float4(y.x-2.f*ym1.x+ym2.x, y.y-2.f*ym1.y+ym2.y,
                            y.z-2.f*ym1.z+ym2.z, y.w-2.f*ym1.w+ym2.w);
    union { unsigned short u16[4]; uint2 v; } p;
    unsigned short* base = &yS[r*ASTRIDE + d4*4];
    p.u16[0]=f2bf(y.x);  p.u16[1]=f2bf(y.y);  p.u16[2]=f2bf(y.z);  p.u16[3]=f2bf(y.w);
    *(uint2*)(base)        = p.v;
    p.u16[0]=f2bf(d1.x); p.u16[1]=f2bf(d1.y); p.u16[2]=f2bf(d1.z); p.u16[3]=f2bf(d1.w);
    *(uint2*)(base + 256)  = p.v;
    p.u16[0]=f2bf(d2.x); p.u16[1]=f2bf(d2.y); p.u16[2]=f2bf(d2.z); p.u16[3]=f2bf(d2.w);
    *(uint2*)(base + 512)  = p.v;
  }
  __syncthreads();

  int wv   = __builtin_amdgcn_readfirstlane(t >> 6);
  int lane = t & 63, quad = lane >> 4, ln = lane & 15;
  int c0 = wv*2;
  floatx4 acc[3][2];
  #pragma unroll
  for (int i = 0; i < 3; ++i){
    acc[i][0] = (floatx4){0.f,0.f,0.f,0.f};
    acc[i][1] = (floatx4){0.f,0.f,0.f,0.f};
  }
  #pragma unroll
  for (int kt = 0; kt < 24; ++kt){
    int aoff = kt*32 + quad*8;
    short8 a0 = *(const short8*)&yS[( 0 + ln)*ASTRIDE + aoff];
    short8 a1 = *(const short8*)&yS[(16 + ln)*ASTRIDE + aoff];
    short8 a2 = *(const short8*)&yS[(32 + ln)*ASTRIDE + aoff];
    short8 b0 = *(const short8*)&Bsw[((kt*8 + c0  )*64 + lane)*8];
    short8 b1 = *(const short8*)&Bsw[((kt*8 + c0+1)*64 + lane)*8];
    acc[0][0] = __builtin_amdgcn_mfma_f32_16x16x32_bf16(a0, b0, acc[0][0], 0, 0, 0);
    acc[0][1] = __builtin_amdgcn_mfma_f32_16x16x32_bf16(a0, b1, acc[0][1], 0, 0, 0);
    acc[1][0] = __builtin_amdgcn_mfma_f32_16x16x32_bf16(a1, b0, acc[1][0], 0, 0, 0);
    acc[1][1] = __builtin_amdgcn_mfma_f32_16x16x32_bf16(a1, b1, acc[1][1], 0, 0, 0);
    acc[2][0] = __builtin_amdgcn_mfma_f32_16x16x32_bf16(a2, b0, acc[2][0], 0, 0, 0);
    acc[2][1] = __builtin_amdgcn_mfma_f32_16x16x32_bf16(a2, b1, acc[2][1], 0, 0, 0);
  }

  float bias0 = bb[c0*16 + ln], bias1 = bb[(c0+1)*16 + ln];
  #pragma unroll
  for (int rt = 0; rt < 3; ++rt){
    #pragma unroll
    for (int reg = 0; reg < 4; ++reg){
      int lrow = rt*16 + quad*4 + reg;
      size_t row = (size_t)b*Hn + h0 + lrow;
      float v0 = acc[rt][0][reg] + bias0;
      float v1 = acc[rt][1][reg] + bias1;
      fpos[row*EMBn + c0*16 + ln]     = v0;
      fpos[row*EMBn + (c0+1)*16 + ln] = v1;
      float sq = v0*v0 + v1*v1;
      sq += __shfl_xor(sq, 1); sq += __shfl_xor(sq, 2);
      sq += __shfl_xor(sq, 4); sq += __shfl_xor(sq, 8);
      if (ln == 0) rsq[wv][lrow] = sq;
    }
  }
  __syncthreads();
  if (t < FROWS){
    float s = rsq[0][t] + rsq[1][t] + rsq[2][t] + rsq[3][t];
    finv[(size_t)b*Hn + h0 + t] = 1.f/(sqrtf(s) + 1e-8f);
  }
}

// ---------- 6. MSE of gated fusion ----------
__global__ void k_mse(const float* __restrict__ yres, const float* __restrict__ yfut,
                      const float* __restrict__ gate, const float* __restrict__ ytirs,
                      const float* __restrict__ Wt, const float* __restrict__ bt,
                      const float* __restrict__ vp, float* __restrict__ part_mse){
  const long long total = (long long)Bn*Hn*Dn;
  long long tid = blockIdx.x*(long long)blockDim.x + threadIdx.x;
  long long nth = gridDim.x*(long long)blockDim.x;
  float part = 0.f;
  for (long long i4 = tid; i4*4 < total; i4 += nth){
    long long base = i4*4;
    int b = (int)(base/((long long)Hn*Dn));
    int rem = (int)(base - (long long)b*Hn*Dn);
    int h = rem/Dn, d = rem - h*Dn;
    float4 yr = *(const float4*)(yres + base);
    float4 yv = *(const float4*)(yfut + base);
    float4 g  = *(const float4*)(gate + (size_t)b*Dn + d);
    float4 wt = *(const float4*)(Wt + d);
    float4 bv = *(const float4*)(bt + d);
    float4 vv = *(const float4*)(vp + d);
    float ys = ytirs[b*Hn + h];
    float yt, yh, e;
    yt = (ys*wt.x + bv.x)*vv.x; yh = yr.x + 0.5f*g.x*(yt-yr.x); e = yh-yv.x; part += e*e;
    yt = (ys*wt.y + bv.y)*vv.y; yh = yr.y + 0.5f*g.y*(yt-yr.y); e = yh-yv.y; part += e*e;
    yt = (ys*wt.z + bv.z)*vv.z; yh = yr.z + 0.5f*g.z*(yt-yr.z); e = yh-yv.z; part += e*e;
    yt = (ys*wt.w + bv.w)*vv.w; yh = yr.w + 0.5f*g.w*(yt-yr.w); e = yh-yv.w; part += e*e;
  }
  __shared__ float red[256];
  red[threadIdx.x] = part; __syncthreads();
  for (int s = 128; s > 0; s >>= 1){
    if (threadIdx.x < s) red[threadIdx.x] += red[threadIdx.x + s];
    __syncthreads();
  }
  if (threadIdx.x == 0) part_mse[blockIdx.x] = red[0];
}

// ---------- 7a. cost: Km[b][k][h] = exp(-20*C) ----------
__global__ __launch_bounds__(256) void k_cost(const float* __restrict__ kn,
    const float* __restrict__ fpos, const float* __restrict__ finv,
    const float* __restrict__ mu_i, float* __restrict__ Km_g){
  int b = blockIdx.x, t = threadIdx.x;
  __shared__ float knS[Kn*132];   // pad 132: float4-aligned, conflict-light
  __shared__ float musS[Kn];
  for (int j = t; j < Kn*EMBn; j += 256){
    int k = j >> 7, e = j & 127;
    knS[k*132 + e] = kn[(size_t)b*Kn*EMBn + j];
  }
  if (t < Kn) musS[t] = mu_i[b*Kn + t];
  __syncthreads();
  for (int p = t; p < Kn*Hn; p += 256){
    int k = p & 15, h = p >> 4;          // k inner: 16-lane groups share h -> broadcast fpos reads
    const float4* f4 = (const float4*)(fpos + ((size_t)b*Hn + h)*EMBn);
    const float4* k4 = (const float4*)(knS + k*132);
    float s = 0.f;
    #pragma unroll 8
    for (int i = 0; i < EMBn/4; ++i){
      float4 a = k4[i], f = f4[i];
      s += a.x*f.x + a.y*f.y + a.z*f.z + a.w*f.w;
    }
    float cs = s*finv[b*Hn + h];
    float th = (h + 0.5f)/(float)Hn;
    float c  = (1.f - cs) + 0.5f*fmaxf(musS[k] - th, 0.f);
    Km_g[(size_t)b*Kn*Hn + k*Hn + h] = expf(-20.f*c);
  }
}

// ---------- 7b. Sinkhorn: one wave per batch, Km in registers, zero barriers ----------
__global__ __launch_bounds__(64) void k_sink1w(const float* __restrict__ rr,
    float* KmwT, float* __restrict__ part_cot){
  int b = blockIdx.x, l = threadIdx.x;
  float* Kb = KmwT + (size_t)b*Kn*Hn;
  float km[Kn][6];
  #pragma unroll
  for (int i = 0; i < 6; ++i){
    int h = 64*i + l;
    bool ok = (h < Hn);
    #pragma unroll
    for (int k = 0; k < Kn; ++k) km[k][i] = ok ? Kb[k*Hn + h] : 0.f;
  }
  float rrl[Kn];
  #pragma unroll
  for (int k = 0; k < Kn; ++k) rrl[k] = rr[b*Kn + k];
  float v[6];
  #pragma unroll
  for (int i = 0; i < 6; ++i) v[i] = 1.f;
  float u[Kn];
  for (int it = 0; it < 30; ++it){
    #pragma unroll
    for (int k = 0; k < Kn; ++k){
      float p = km[k][0]*v[0];
      #pragma unroll
      for (int i = 1; i < 6; ++i) p += km[k][i]*v[i];
      p = wsum(p);
      u[k] = rrl[k]*rcpf(p + 1e-9f);
    }
    #pragma unroll
    for (int i = 0; i < 6; ++i){
      float s = km[0][i]*u[0];
      #pragma unroll
      for (int k = 1; k < Kn; ++k) s += km[k][i]*u[k];
      v[i] = (1.f/(float)Hn)*rcpf(s + 1e-9f);
    }
  }
  // cot + wT (in-place overwrite of Km; this block's slice only, values already in regs)
  float cot = 0.f;
  #pragma unroll
  for (int k = 0; k < Kn; ++k){
    float p = km[k][0]*v[0];
    #pragma unroll
    for (int i = 1; i < 6; ++i) p += km[k][i]*v[i];
    p = wsum(p);
    float rsinv = rcpf(u[k]*p + 1e-9f);
    #pragma unroll
    for (int i = 0; i < 6; ++i){
      int h = 64*i + l;
      if (h < Hn){
        float Pi = u[k]*km[k][i]*v[i];
        cot += (-0.05f)*logf(km[k][i])*Pi;   // C = -eps*ln(Km)
        Kb[k*Hn + h] = Pi*rsinv;             // wT[b][k][h]
      }
    }
  }
  cot = wsum(cot);
  if (l == 0) part_cot[b] = cot;
}

// ---------- 7c. agg + delta-contrastive ----------
__global__ __launch_bounds__(256) void k_agg(const float* __restrict__ kn,
    const float* __restrict__ fpos, const float* __restrict__ wT,
    const int* __restrict__ perm, float* __restrict__ part_del){
  int b = blockIdx.x, t = threadIdx.x;
  __shared__ float wTl[Hn*20];          // pad 20: 80B row stride, 16B-aligned float4s
  __shared__ float aggp[Kn*EMBn];
  __shared__ float agg1[Kn*EMBn];
  __shared__ int permS[EMBn];
  __shared__ float redW[4];
  if (t < EMBn) permS[t] = perm[t];
  for (int j = t; j < Kn*Hn; j += 256){
    int k = j/Hn, h = j - k*Hn;
    wTl[h*20 + k] = wT[(size_t)b*Kn*Hn + j];
  }
  __syncthreads();

  {
    int e = t & 127, kg = __builtin_amdgcn_readfirstlane(t >> 7);
    float ap[8], a1[8];
    #pragma unroll
    for (int j = 0; j < 8; ++j){ ap[j] = 0.f; a1[j] = 0.f; }
    for (int h = 0; h < Hn; ++h){
      float fv = fpos[((size_t)b*Hn + h)*EMBn + e];
      int h1 = h + SHIFT; if (h1 >= Hn) h1 -= Hn;
      float4 wA0 = *(const float4*)&wTl[h *20 + kg*8];
      float4 wA1 = *(const float4*)&wTl[h *20 + kg*8 + 4];
      float4 wB0 = *(const float4*)&wTl[h1*20 + kg*8];
      float4 wB1 = *(const float4*)&wTl[h1*20 + kg*8 + 4];
      ap[0] += wA0.x*fv; ap[1] += wA0.y*fv; ap[2] += wA0.z*fv; ap[3] += wA0.w*fv;
      ap[4] += wA1.x*fv; ap[5] += wA1.y*fv; ap[6] += wA1.z*fv; ap[7] += wA1.w*fv;
      a1[0] += wB0.x*fv; a1[1] += wB0.y*fv; a1[2] += wB0.z*fv; a1[3] += wB0.w*fv;
      a1[4] += wB1.x*fv; a1[5] += wB1.y*fv; a1[6] += wB1.z*fv; a1[7] += wB1.w*fv;
    }
    #pragma unroll
    for (int j = 0; j < 8; ++j){
      int k = kg*8 + j;
      aggp[k*EMBn + e] = ap[j];
      agg1[k*EMBn + e] = a1[j];
    }
  }
  __syncthreads();

  int wave = t >> 6, lane = t & 63;
  float dsum = 0.f;
  for (int i = 0; i < 4; ++i){
    int k = wave*4 + i;
    float sp = 0.f, s1 = 0.f, s2 = 0.f, np = 0.f, n1 = 0.f;
    for (int e = lane; e < EMBn; e += 64){
      float kne = kn[((size_t)b*Kn + k)*EMBn + e];
      float a  = aggp[k*EMBn + e];
      float c1 = agg1[k*EMBn + e];
      sp += kne*a; s1 += kne*c1;
      s2 += kne*aggp[k*EMBn + permS[e]];
      np += a*a; n1 += c1*c1;
    }
    for (int o = 32; o; o >>= 1){
      sp += __shfl_down(sp, o); s1 += __shfl_down(s1, o); s2 += __shfl_down(s2, o);
      np += __shfl_down(np, o); n1 += __shfl_down(n1, o);
    }
    if (lane == 0){
      float ip  = 1.f/(sqrtf(np) + 1e-8f);
      float i1v = 1.f/(sqrtf(n1) + 1e-8f);
      const float ti = 1.f/0.07f;
      float l0 = sp*ip*ti, l1 = s1*i1v*ti, l2 = s2*ip*ti;
      float m = fmaxf(l0, fmaxf(l1, l2));
      float lse = m + logf(expf(l0-m) + expf(l1-m) + expf(l2-m));
      dsum += (lse - l0);
    }
  }
  __syncthreads();
  if (lane == 0) redW[wave] = dsum;
  __syncthreads();
  if (t == 0) part_del[b] = redW[0] + redW[1] + redW[2] + redW[3];
}

// ---------- 8. combine ----------
__global__ void k_final(const float* __restrict__ part_mse, const float* __restrict__ part_cot,
                        const float* __restrict__ part_del, const float* __restrict__ part_ent,
                        const float* __restrict__ part_tv, float* __restrict__ out){
  int t = threadIdx.x;  // 256
  __shared__ double sred[256];
  double m = 0.0;
  for (int i = t; i < MSEB; i += 256) m += (double)part_mse[i];
  double o4 = 0.0;
  if (t < Bn){
    o4 = 0.1*(double)part_cot[t] + (0.1/(double)Kn)*(double)part_del[t]
       - (0.01/(double)Kn)*(double)part_ent[t] + (0.01/(double)(Kn-1))*(double)part_tv[t];
  }
  sred[t] = m/((double)Bn*Hn*Dn) + o4/(double)Bn;
  __syncthreads();
  for (int s = 128; s > 0; s >>= 1){ if (t < s) sred[t] += sred[t+s]; __syncthreads(); }
  if (t == 0) out[0] = (float)sred[0];
}

// ---------- launch ----------
extern "C" void kernel_launch(void* const* d_in, const int* in_sizes, int n_in,
                              void* d_out, int out_size, void* d_ws, size_t ws_size,
                              hipStream_t stream) {
  const float* y_res  = (const float*)d_in[0];
  const float* text   = (const float*)d_in[1];
  const float* enc    = (const float*)d_in[2];
  const float* yfut   = (const float*)d_in[3];
  const int*   perm   = (const int*)  d_in[4];
  const float* W_t2k  = (const float*)d_in[5];
  const float* b_t2k  = (const float*)d_in[6];
  const float* W_kemb = (const float*)d_in[7];
  const float* b_kemb = (const float*)d_in[8];
  const float* W_tir  = (const float*)d_in[9];
  const float* b_tir  = (const float*)d_in[10];
  const float* vproj  = (const float*)d_in[11];
  const float* W_g1   = (const float*)d_in[12];
  const float* b_g1   = (const float*)d_in[13];
  const float* W_g2   = (const float*)d_in[14];
  const float* b_g2   = (const float*)d_in[15];
  const float* W_fp   = (const float*)d_in[16];
  const float* b_fp   = (const float*)d_in[17];

  float* F = (float*)d_ws;
  float* mu_w   = F;            // 2048
  float* rr_w   = F + 2048;     // 2048
  float* ytr_w  = F + 4096;     // 43008
  float* kapT_w = F + 47104;    // 688128  (lifecycle: kapT -> Bsw -> Km -> wT)
  float* kn_w   = F + 735232;   // 262144
  float* gate_w = F + 997376;   // 32768
  float* fp_w   = F + 1030144;  // 5505024
  float* fi_w   = F + 6535168;  // 43008
  float* pmse_w = F + 6578176;  // 1024
  float* pcot_w = F + 6579200;  // 128
  float* pdel_w = F + 6579328;  // 128
  float* pent_w = F + 6579456;  // 128
  float* ptv_w  = F + 6579584;  // 128
  unsigned short* Bsw_w = (unsigned short*)kapT_w;  // 192 KB, dead after k_fposm
  float* KmwT_w = kapT_w;                            // 2.75 MB, exact-size overlay

  k_fused1<<<Bn, 128, 0, stream>>>(text, W_t2k, b_t2k, mu_w, kapT_w, rr_w, ytr_w, pent_w, ptv_w);
  k_kemb  <<<Bn, 128, 0, stream>>>(kapT_w, W_kemb, b_kemb, kn_w);
  k_wprep <<<384, 256, 0, stream>>>(W_fp, Bsw_w);
  k_gate  <<<Bn, 512, 0, stream>>>(enc, text, vproj, W_g1, b_g1, W_g2, b_g2, gate_w);
  k_fposm <<<Bn*FTILES, 256, 0, stream>>>(yfut, Bsw_w, b_fp, fp_w, fi_w);
  k_mse   <<<MSEB, 256, 0, stream>>>(y_res, yfut, gate_w, ytr_w, W_tir, b_tir, vproj, pmse_w);
  k_cost  <<<Bn, 256, 0, stream>>>(kn_w, fp_w, fi_w, mu_w, KmwT_w);
  k_sink1w<<<Bn, 64, 0, stream>>>(rr_w, KmwT_w, pcot_w);
  k_agg   <<<Bn, 256, 0, stream>>>(kn_w, fp_w, KmwT_w, perm, pdel_w);
  k_final <<<1, 256, 0, stream>>>(pmse_w, pcot_w, pdel_w, pent_w, ptv_w, (float*)d_out);
}